// Round 10
// baseline (684.431 us; speedup 1.0000x reference)
//
#include <hip/hip_runtime.h>
#include <cstdint>
#include <cstddef>

#define CH 256      // all layers are 256-channel

typedef _Float16 f16x8 __attribute__((ext_vector_type(8)));
typedef _Float16 f16x4 __attribute__((ext_vector_type(4)));
typedef float f32x4 __attribute__((ext_vector_type(4)));

// ---------------- helpers ----------------

__device__ __forceinline__ int ld_idx(const void* p, long long i, int w64) {
    if (w64) return (int)((const long long*)p)[i];
    return ((const int*)p)[i];
}

__device__ __forceinline__ float gelu_f(float x) {
    float x3 = x * x * x;
    float t = tanhf(0.7978845608028654f * (x + 0.044715f * x3));
    return 0.5f * x * (1.0f + t);
}

// ---------------- preprocessing ----------------

__global__ void k_detect(const void* __restrict__ ei, int* __restrict__ flag, int E) {
    int l = threadIdx.x;  // 0..63
    long long k = ((long long)l * (long long)(E - 1)) / 63;
    int w = ((const int*)ei)[2 * k + 1];
    unsigned long long vote = __ballot(w == 0);
    if (l == 0) *flag = (vote == ~0ULL) ? 1 : 0;
}

__global__ void k_deg(const void* __restrict__ ei, const int* __restrict__ flag,
                      int* __restrict__ deg, int E) {
    int e = blockIdx.x * blockDim.x + threadIdx.x;
    if (e >= E) return;
    int w64 = *flag;
    int d = ld_idx(ei, (long long)E + e, w64);
    atomicAdd(&deg[d], 1);
}

__global__ void k_dis(const int* __restrict__ deg, float* __restrict__ dis, int N) {
    int n = blockIdx.x * blockDim.x + threadIdx.x;
    if (n >= N) return;
    dis[n] = 1.0f / sqrtf((float)(deg[n] + 1));
}

__global__ void k_scan_block(const int* __restrict__ deg, int* __restrict__ rowptr,
                             int* __restrict__ partial, int N) {
    __shared__ int s[256];
    int gid = blockIdx.x * 256 + threadIdx.x;
    int v = (gid < N) ? deg[gid] : 0;
    s[threadIdx.x] = v;
    __syncthreads();
    for (int off = 1; off < 256; off <<= 1) {
        int t = (threadIdx.x >= off) ? s[threadIdx.x - off] : 0;
        __syncthreads();
        s[threadIdx.x] += t;
        __syncthreads();
    }
    if (gid < N) rowptr[gid] = s[threadIdx.x] - v;
    if (threadIdx.x == 255) partial[blockIdx.x] = s[255];
}

__global__ void k_scan_partial(int* __restrict__ partial, int nb) {
    __shared__ int s[256];
    int i = threadIdx.x;
    int v = (i < nb) ? partial[i] : 0;
    s[i] = v;
    __syncthreads();
    for (int off = 1; off < 256; off <<= 1) {
        int t = (i >= off) ? s[i - off] : 0;
        __syncthreads();
        s[i] += t;
        __syncthreads();
    }
    if (i < nb) partial[i] = s[i] - v;
}

__global__ void k_add_off(int* __restrict__ rowptr, const int* __restrict__ partial,
                          int N, int E) {
    int gid = blockIdx.x * 256 + threadIdx.x;
    if (gid < N) rowptr[gid] += partial[blockIdx.x];
    if (gid == 0) rowptr[N] = E;
}

__global__ void k_scatter(const void* __restrict__ ei, const int* __restrict__ flag,
                          const float* __restrict__ dis, const int* __restrict__ rowptr,
                          int* __restrict__ cnt, int2* __restrict__ epack, int E) {
    int e = blockIdx.x * blockDim.x + threadIdx.x;
    if (e >= E) return;
    int w64 = *flag;
    int s = ld_idx(ei, e, w64);
    int d = ld_idx(ei, (long long)E + e, w64);
    int pos = rowptr[d] + atomicAdd(&cnt[d], 1);
    epack[pos] = make_int2(s, __float_as_int(dis[s] * dis[d]));
}

// ---------------- weight split: W[k][c] fp32 -> Wt hi/lo fp16 [c][k] ----------------

__global__ void k_split_w(const float* __restrict__ W, _Float16* __restrict__ Wh,
                          _Float16* __restrict__ Wl) {
    int k = threadIdx.x;   // 0..255
    int c = blockIdx.x;    // 0..255
    float v = W[k * CH + c];
    _Float16 h = (_Float16)v;
    Wh[c * CH + k] = h;
    Wl[c * CH + k] = (_Float16)(v - (float)h);
}

// ---------------- input quantize: fp32 x -> int16 rows + per-node scale ----------------

__global__ __launch_bounds__(256) void k_quant_x(const float* __restrict__ x,
                                                 uint8_t* __restrict__ Xout,
                                                 float* __restrict__ sout, int N) {
    int node = blockIdx.x * 4 + threadIdx.y;
    if (node >= N) return;
    int lane = threadIdx.x;
    float4 v = ((const float4*)(x + (size_t)node * CH))[lane];
    float mx = fmaxf(fmaxf(fabsf(v.x), fabsf(v.y)), fmaxf(fabsf(v.z), fabsf(v.w)));
    #pragma unroll
    for (int off = 32; off > 0; off >>= 1)
        mx = fmaxf(mx, __shfl_xor(mx, off));
    float inv = (mx > 0.f) ? (32767.0f / mx) : 0.f;
    short4 q;
    q.x = (short)__float2int_rn(v.x * inv);
    q.y = (short)__float2int_rn(v.y * inv);
    q.z = (short)__float2int_rn(v.z * inv);
    q.w = (short)__float2int_rn(v.w * inv);
    *(short4*)(Xout + (size_t)node * 512 + (size_t)lane * 8) = q;
    if (lane == 0) sout[node] = mx * (1.0f / 32767.0f);
}

// ---------------- fused layer: gather-agg -> GEMM -> bias(+gelu) -> quantize ------
// agg(X)@W == agg(X@W)  (segment-sum commutes with the dense transform).
// Block = 32 nodes, 512 threads (8 waves).
// Phase 1: each wave gathers 4 nodes (64 lanes x 4ch int16 gather, fp32 accum),
//          writes aggregate as fp16 hi/lo planes into XOR-swizzled LDS.
// Phase 2: barrier-free MFMA k-loop (Y is read-only): wave w -> rows 16*(w&1),
//          cols 64*(w>>1); B fragments streamed from L2-resident W planes.
// Phase 3: bias (+gelu), block absmax, int16 quantize to Xout (MODE 0)
//          or fp32 store to out (MODE 1).

template <int MODE>
__global__ __launch_bounds__(512, 4)
void k_layer(const uint8_t* __restrict__ Xin, const float* __restrict__ sin_,
             const _Float16* __restrict__ Bh, const _Float16* __restrict__ Bl,
             const float* __restrict__ dis, const int* __restrict__ rowptr,
             const int2* __restrict__ epack, const float* __restrict__ bias,
             uint8_t* __restrict__ Xout, float* __restrict__ sout,
             float* __restrict__ out, int N) {
    __shared__ __align__(16) char smem[32768 + 64];
    float* red = (float*)(smem + 32768);

    const int tid  = threadIdx.x;
    const int lane = tid & 63;
    const int wid  = tid >> 6;            // 0..7
    const int m0   = blockIdx.x * 32;

    // ---- phase 1: gather-aggregate, 4 nodes per wave ----
    #pragma unroll 1
    for (int q = 0; q < 4; q++) {
        int row = wid * 4 + q;            // 0..31
        int node = m0 + row;
        int cn = (node < N) ? node : (N - 1);   // clamp: duplicate data, no NaN
        float d = dis[cn];
        short4 hv = *(const short4*)(Xin + (size_t)cn * 512 + (size_t)lane * 8);
        float wself = d * d * sin_[cn];
        float ax = wself * (float)hv.x, ay = wself * (float)hv.y;
        float az = wself * (float)hv.z, aw = wself * (float)hv.w;
        int s = rowptr[cn], e = rowptr[cn + 1];
        int j = s;
        for (; j + 8 <= e; j += 8) {
            int2 p[8];
            #pragma unroll
            for (int t = 0; t < 8; t++) p[t] = epack[j + t];
            short4 v[8];
            float sc[8];
            #pragma unroll
            for (int t = 0; t < 8; t++) {
                v[t] = *(const short4*)(Xin + (size_t)p[t].x * 512 + (size_t)lane * 8);
                sc[t] = sin_[p[t].x];
            }
            #pragma unroll
            for (int t = 0; t < 8; t++) {
                float wn = __int_as_float(p[t].y) * sc[t];
                ax += wn * (float)v[t].x; ay += wn * (float)v[t].y;
                az += wn * (float)v[t].z; aw += wn * (float)v[t].w;
            }
        }
        for (; j < e; j++) {
            int2 p = epack[j];
            float wn = __int_as_float(p.y) * sin_[p.x];
            short4 v = *(const short4*)(Xin + (size_t)p.x * 512 + (size_t)lane * 8);
            ax += wn * (float)v.x; ay += wn * (float)v.y;
            az += wn * (float)v.z; aw += wn * (float)v.w;
        }
        // split to fp16 hi/lo, write swizzled LDS (lane owns ch 4*lane..4*lane+3)
        f16x4 h, l;
        h[0] = (_Float16)ax; l[0] = (_Float16)(ax - (float)h[0]);
        h[1] = (_Float16)ay; l[1] = (_Float16)(ay - (float)h[1]);
        h[2] = (_Float16)az; l[2] = (_Float16)(az - (float)h[2]);
        h[3] = (_Float16)aw; l[3] = (_Float16)(aw - (float)h[3]);
        int chunk = lane >> 1;                         // 16B chunk 0..31
        int off = row * 512 + (((chunk) ^ (row & 7)) << 4) + (lane & 1) * 8;
        *(uint2*)(smem + off)         = *(uint2*)&h;
        *(uint2*)(smem + 16384 + off) = *(uint2*)&l;
    }
    __syncthreads();

    // ---- phase 2: GEMM (no barriers in k-loop; Y read-only) ----
    const int wm = wid & 1, wn = wid >> 1;     // wm: row group of 16; wn: col group of 64
    const int r15 = lane & 15, kg = lane >> 4;
    const int arow = wm * 16 + r15;
    const int arsw = arow & 7;

    f32x4 acc[4];
    #pragma unroll
    for (int n = 0; n < 4; n++) acc[n] = (f32x4){0.f, 0.f, 0.f, 0.f};

    #pragma unroll
    for (int ks = 0; ks < 8; ks++) {
        f16x8 bh[4], bl[4];
        #pragma unroll
        for (int n = 0; n < 4; n++) {
            int C = wn * 64 + n * 16 + r15;
            bh[n] = *(const f16x8*)(Bh + (size_t)C * CH + ks * 32 + kg * 8);
            bl[n] = *(const f16x8*)(Bl + (size_t)C * CH + ks * 32 + kg * 8);
        }
        int chunk = 4 * ks + kg;
        int aoff = arow * 512 + (((chunk) ^ arsw) << 4);
        f16x8 ah = *(const f16x8*)(smem + aoff);
        f16x8 al = *(const f16x8*)(smem + 16384 + aoff);
        #pragma unroll
        for (int n = 0; n < 4; n++) {
            acc[n] = __builtin_amdgcn_mfma_f32_16x16x32_f16(ah, bh[n], acc[n], 0, 0, 0);
            acc[n] = __builtin_amdgcn_mfma_f32_16x16x32_f16(ah, bl[n], acc[n], 0, 0, 0);
            acc[n] = __builtin_amdgcn_mfma_f32_16x16x32_f16(al, bh[n], acc[n], 0, 0, 0);
        }
    }
    __syncthreads();   // all Y reads complete before LDS reuse

    // ---- phase 3: bias (+gelu), absmax, write fp32 tile to LDS ----
    float mx = 0.f;
    float vals[4][4];
    #pragma unroll
    for (int n = 0; n < 4; n++) {
        int col = wn * 64 + n * 16 + r15;
        float b = bias[col];
        #pragma unroll
        for (int r = 0; r < 4; r++) {
            float v = acc[n][r] + b;
            if (MODE == 0) v = gelu_f(v);
            vals[n][r] = v;
            mx = fmaxf(mx, fabsf(v));
        }
    }
    #pragma unroll
    for (int n = 0; n < 4; n++) {
        int col = wn * 64 + n * 16 + r15;
        int c = col >> 2;
        #pragma unroll
        for (int r = 0; r < 4; r++) {
            int rr = wm * 16 + kg * 4 + r;
            *(float*)(smem + rr * 1024 + (((c) ^ (rr & 7)) << 4) + (col & 3) * 4) = vals[n][r];
        }
    }
    #pragma unroll
    for (int off = 32; off > 0; off >>= 1)
        mx = fmaxf(mx, __shfl_xor(mx, off));
    if (lane == 0) red[wid] = mx;
    __syncthreads();

    // ---- output: quantize (MODE 0) or fp32 (MODE 1) ----
    int row = tid >> 4;            // 0..31
    int jj = tid & 15;             // 16 threads per row, 16 ch each
    int grow = m0 + row;
    if (MODE == 0) {
        float tmax = 0.f;
        #pragma unroll
        for (int i = 0; i < 8; i++) tmax = fmaxf(tmax, red[i]);
        float inv = (tmax > 0.f) ? (32767.0f / tmax) : 0.f;
        if (grow < N) {
            unsigned pk[8];
            #pragma unroll
            for (int cc = 0; cc < 4; cc++) {
                int c = jj * 4 + cc;
                f32x4 v = *(const f32x4*)(smem + row * 1024 + (((c) ^ (row & 7)) << 4));
                int q0 = __float2int_rn(v[0] * inv);
                int q1 = __float2int_rn(v[1] * inv);
                int q2 = __float2int_rn(v[2] * inv);
                int q3 = __float2int_rn(v[3] * inv);
                pk[cc * 2 + 0] = (q0 & 0xFFFF) | (q1 << 16);
                pk[cc * 2 + 1] = (q2 & 0xFFFF) | (q3 << 16);
            }
            uint8_t* dst = Xout + (size_t)grow * 512 + (size_t)jj * 32;
            *(uint4*)dst = make_uint4(pk[0], pk[1], pk[2], pk[3]);
            *(uint4*)(dst + 16) = make_uint4(pk[4], pk[5], pk[6], pk[7]);
        }
        if (tid < 32 && m0 + tid < N) sout[m0 + tid] = tmax * (1.0f / 32767.0f);
    } else {
        if (grow < N) {
            #pragma unroll
            for (int cc = 0; cc < 4; cc++) {
                int c = jj * 4 + cc;
                f32x4 v = *(const f32x4*)(smem + row * 1024 + (((c) ^ (row & 7)) << 4));
                *(f32x4*)(out + (size_t)grow * CH + c * 4) = v;
            }
        }
    }
}

// ---------------- launcher ----------------

extern "C" void kernel_launch(void* const* d_in, const int* in_sizes, int n_in,
                              void* d_out, int out_size, void* d_ws, size_t ws_size,
                              hipStream_t stream) {
    const float* x  = (const float*)d_in[0];
    const void*  ei = d_in[1];
    const float* W1 = (const float*)d_in[3]; const float* b1 = (const float*)d_in[4];
    const float* W2 = (const float*)d_in[5]; const float* b2 = (const float*)d_in[6];
    const float* W3 = (const float*)d_in[7]; const float* b3 = (const float*)d_in[8];

    int N = in_sizes[0] / CH;
    int E = in_sizes[1] / 2;
    float* out = (float*)d_out;

    char* ws = (char*)d_ws;
    auto take = [&](size_t bytes) {
        char* p = ws;
        ws += (bytes + 15) & ~(size_t)15;
        return p;
    };
    uint8_t*  Xa     = (uint8_t*) take((size_t)N * 512);
    uint8_t*  Xb     = (uint8_t*) take((size_t)N * 512);
    float*    sa     = (float*)   take((size_t)N * sizeof(float));
    float*    sb     = (float*)   take((size_t)N * sizeof(float));
    int*      deg    = (int*)     take((size_t)N * sizeof(int));
    float*    dis    = (float*)   take((size_t)N * sizeof(float));
    int*      rowptr = (int*)     take((size_t)(N + 1) * sizeof(int));
    int*      cnt    = (int*)     take((size_t)N * sizeof(int));
    int*      part   = (int*)     take(4096);
    int*      flag   = (int*)     take(16);
    int2*     epack  = (int2*)    take((size_t)E * sizeof(int2));
    _Float16* Wh1    = (_Float16*)take((size_t)CH * CH * 2);
    _Float16* Wl1    = (_Float16*)take((size_t)CH * CH * 2);
    _Float16* Wh2    = (_Float16*)take((size_t)CH * CH * 2);
    _Float16* Wl2    = (_Float16*)take((size_t)CH * CH * 2);
    _Float16* Wh3    = (_Float16*)take((size_t)CH * CH * 2);
    _Float16* Wl3    = (_Float16*)take((size_t)CH * CH * 2);

    hipMemsetAsync(deg, 0, (size_t)N * sizeof(int), stream);
    hipMemsetAsync(cnt, 0, (size_t)N * sizeof(int), stream);

    int eb = (E + 255) / 256;
    int nb = (N + 255) / 256;

    k_detect<<<1, 64, 0, stream>>>(ei, flag, E);
    k_deg<<<eb, 256, 0, stream>>>(ei, flag, deg, E);
    k_dis<<<nb, 256, 0, stream>>>(deg, dis, N);
    k_scan_block<<<nb, 256, 0, stream>>>(deg, rowptr, part, N);
    k_scan_partial<<<1, 256, 0, stream>>>(part, nb);
    k_add_off<<<nb, 256, 0, stream>>>(rowptr, part, N, E);
    k_scatter<<<eb, 256, 0, stream>>>(ei, flag, dis, rowptr, cnt, epack, E);

    k_split_w<<<CH, CH, 0, stream>>>(W1, Wh1, Wl1);
    k_split_w<<<CH, CH, 0, stream>>>(W2, Wh2, Wl2);
    k_split_w<<<CH, CH, 0, stream>>>(W3, Wh3, Wl3);

    dim3 qgrid((N + 3) / 4);
    dim3 qblock(64, 4);
    k_quant_x<<<qgrid, qblock, 0, stream>>>(x, Xa, sa, N);

    dim3 lgrid((N + 31) / 32);

    // layer 1: Xa -> Xb
    k_layer<0><<<lgrid, 512, 0, stream>>>(Xa, sa, Wh1, Wl1, dis, rowptr, epack, b1,
                                          Xb, sb, out, N);
    // layer 2: Xb -> Xa
    k_layer<0><<<lgrid, 512, 0, stream>>>(Xb, sb, Wh2, Wl2, dis, rowptr, epack, b2,
                                          Xa, sa, out, N);
    // layer 3: Xa -> out (fp32, no gelu)
    k_layer<1><<<lgrid, 512, 0, stream>>>(Xa, sa, Wh3, Wl3, dis, rowptr, epack, b3,
                                          Xb, sb, out, N);
}

// Round 11
// 589.074 us; speedup vs baseline: 1.1619x; 1.1619x over previous
//
#include <hip/hip_runtime.h>
#include <cstdint>
#include <cstddef>

#define CH 256      // all layers are 256-channel

typedef _Float16 f16x8 __attribute__((ext_vector_type(8)));
typedef _Float16 f16x4 __attribute__((ext_vector_type(4)));
typedef float f32x4 __attribute__((ext_vector_type(4)));

// ---------------- helpers ----------------

__device__ __forceinline__ int ld_idx(const void* p, long long i, int w64) {
    if (w64) return (int)((const long long*)p)[i];
    return ((const int*)p)[i];
}

__device__ __forceinline__ float gelu_f(float x) {
    float x3 = x * x * x;
    float t = tanhf(0.7978845608028654f * (x + 0.044715f * x3));
    return 0.5f * x * (1.0f + t);
}

// ---------------- preprocessing ----------------

__global__ void k_detect(const void* __restrict__ ei, int* __restrict__ flag, int E) {
    int l = threadIdx.x;  // 0..63
    long long k = ((long long)l * (long long)(E - 1)) / 63;
    int w = ((const int*)ei)[2 * k + 1];
    unsigned long long vote = __ballot(w == 0);
    if (l == 0) *flag = (vote == ~0ULL) ? 1 : 0;
}

__global__ void k_deg(const void* __restrict__ ei, const int* __restrict__ flag,
                      int* __restrict__ deg, int E) {
    int e = blockIdx.x * blockDim.x + threadIdx.x;
    if (e >= E) return;
    int w64 = *flag;
    int d = ld_idx(ei, (long long)E + e, w64);
    atomicAdd(&deg[d], 1);
}

__global__ void k_dis(const int* __restrict__ deg, float* __restrict__ dis, int N) {
    int n = blockIdx.x * blockDim.x + threadIdx.x;
    if (n >= N) return;
    dis[n] = 1.0f / sqrtf((float)(deg[n] + 1));
}

__global__ void k_scan_block(const int* __restrict__ deg, int* __restrict__ rowptr,
                             int* __restrict__ partial, int N) {
    __shared__ int s[256];
    int gid = blockIdx.x * 256 + threadIdx.x;
    int v = (gid < N) ? deg[gid] : 0;
    s[threadIdx.x] = v;
    __syncthreads();
    for (int off = 1; off < 256; off <<= 1) {
        int t = (threadIdx.x >= off) ? s[threadIdx.x - off] : 0;
        __syncthreads();
        s[threadIdx.x] += t;
        __syncthreads();
    }
    if (gid < N) rowptr[gid] = s[threadIdx.x] - v;
    if (threadIdx.x == 255) partial[blockIdx.x] = s[255];
}

__global__ void k_scan_partial(int* __restrict__ partial, int nb) {
    __shared__ int s[256];
    int i = threadIdx.x;
    int v = (i < nb) ? partial[i] : 0;
    s[i] = v;
    __syncthreads();
    for (int off = 1; off < 256; off <<= 1) {
        int t = (i >= off) ? s[i - off] : 0;
        __syncthreads();
        s[i] += t;
        __syncthreads();
    }
    if (i < nb) partial[i] = s[i] - v;
}

__global__ void k_add_off(int* __restrict__ rowptr, const int* __restrict__ partial,
                          int N, int E) {
    int gid = blockIdx.x * 256 + threadIdx.x;
    if (gid < N) rowptr[gid] += partial[blockIdx.x];
    if (gid == 0) rowptr[N] = E;
}

__global__ void k_scatter(const void* __restrict__ ei, const int* __restrict__ flag,
                          const float* __restrict__ dis, const int* __restrict__ rowptr,
                          int* __restrict__ cnt, int2* __restrict__ epack, int E) {
    int e = blockIdx.x * blockDim.x + threadIdx.x;
    if (e >= E) return;
    int w64 = *flag;
    int s = ld_idx(ei, e, w64);
    int d = ld_idx(ei, (long long)E + e, w64);
    int pos = rowptr[d] + atomicAdd(&cnt[d], 1);
    epack[pos] = make_int2(s, __float_as_int(dis[s] * dis[d]));
}

// ---------------- weight split: W[k][c] fp32 -> Wt hi/lo fp16 [c][k] ----------------

__global__ void k_split_w(const float* __restrict__ W, _Float16* __restrict__ Wh,
                          _Float16* __restrict__ Wl) {
    int k = threadIdx.x;   // 0..255
    int c = blockIdx.x;    // 0..255
    float v = W[k * CH + c];
    _Float16 h = (_Float16)v;
    Wh[c * CH + k] = h;
    Wl[c * CH + k] = (_Float16)(v - (float)h);
}

// ---------------- input quantize: fp32 x -> int16 rows + per-node scale ----------------

__global__ __launch_bounds__(256) void k_quant_x(const float* __restrict__ x,
                                                 uint8_t* __restrict__ Xout,
                                                 float* __restrict__ sout, int N) {
    int node = blockIdx.x * 4 + threadIdx.y;
    if (node >= N) return;
    int lane = threadIdx.x;
    float4 v = ((const float4*)(x + (size_t)node * CH))[lane];
    float mx = fmaxf(fmaxf(fabsf(v.x), fabsf(v.y)), fmaxf(fabsf(v.z), fabsf(v.w)));
    #pragma unroll
    for (int off = 32; off > 0; off >>= 1)
        mx = fmaxf(mx, __shfl_xor(mx, off));
    float inv = (mx > 0.f) ? (32767.0f / mx) : 0.f;
    short4 q;
    q.x = (short)__float2int_rn(v.x * inv);
    q.y = (short)__float2int_rn(v.y * inv);
    q.z = (short)__float2int_rn(v.z * inv);
    q.w = (short)__float2int_rn(v.w * inv);
    *(short4*)(Xout + (size_t)node * 512 + (size_t)lane * 8) = q;
    if (lane == 0) sout[node] = mx * (1.0f / 32767.0f);
}

// ---------------- fused layer (gather-friendly shape) ----------------
// agg(X)@W == agg(X@W).  Block = 256 threads (4 waves), 16 nodes.
// Phase 1: wave gathers 4 nodes serially (8-deep MLP), writes aggregate
//          as fp16 hi/lo into XOR-swizzled LDS (16 KB).
// Phase 2: M=16 GEMM, wave w -> cols 64w..64w+63; B streamed from L2-resident
//          W planes; zero barriers in the k-loop (Y read-only).
// Phase 3: bias(+gelu), block absmax, int16 quantize -> Xout (MODE 0)
//          or fp32 -> out (MODE 1).

template <int MODE>
__global__ __launch_bounds__(256, 8)
void k_layer(const uint8_t* __restrict__ Xin, const float* __restrict__ sin_,
             const _Float16* __restrict__ Bh, const _Float16* __restrict__ Bl,
             const float* __restrict__ dis, const int* __restrict__ rowptr,
             const int2* __restrict__ epack, const float* __restrict__ bias,
             uint8_t* __restrict__ Xout, float* __restrict__ sout,
             float* __restrict__ out, int N) {
    __shared__ __align__(16) char smem[16384 + 32];
    float* red = (float*)(smem + 16384);

    const int tid  = threadIdx.x;
    const int lane = tid & 63;
    const int wid  = tid >> 6;            // 0..3
    const int m0   = blockIdx.x * 16;

    // ---- phase 1: gather-aggregate, 4 nodes per wave (serial; MLP from unroll) ----
    #pragma unroll 1
    for (int q = 0; q < 4; q++) {
        int row = wid * 4 + q;            // 0..15
        int node = m0 + row;
        int cn = (node < N) ? node : (N - 1);   // clamp: duplicate work, no OOB
        float d = dis[cn];
        short4 hv = *(const short4*)(Xin + (size_t)cn * 512 + (size_t)lane * 8);
        float wself = d * d * sin_[cn];
        float ax = wself * (float)hv.x, ay = wself * (float)hv.y;
        float az = wself * (float)hv.z, aw = wself * (float)hv.w;
        int s = rowptr[cn], e = rowptr[cn + 1];
        int j = s;
        for (; j + 8 <= e; j += 8) {
            int2 p[8];
            #pragma unroll
            for (int t = 0; t < 8; t++) p[t] = epack[j + t];
            short4 v[8];
            float sc[8];
            #pragma unroll
            for (int t = 0; t < 8; t++) {
                v[t] = *(const short4*)(Xin + (size_t)p[t].x * 512 + (size_t)lane * 8);
                sc[t] = sin_[p[t].x];
            }
            #pragma unroll
            for (int t = 0; t < 8; t++) {
                float wn = __int_as_float(p[t].y) * sc[t];
                ax += wn * (float)v[t].x; ay += wn * (float)v[t].y;
                az += wn * (float)v[t].z; aw += wn * (float)v[t].w;
            }
        }
        for (; j < e; j++) {
            int2 p = epack[j];
            float wn = __int_as_float(p.y) * sin_[p.x];
            short4 v = *(const short4*)(Xin + (size_t)p.x * 512 + (size_t)lane * 8);
            ax += wn * (float)v.x; ay += wn * (float)v.y;
            az += wn * (float)v.z; aw += wn * (float)v.w;
        }
        // split hi/lo, write swizzled LDS (lane owns ch 4*lane..4*lane+3)
        f16x4 h, l;
        h[0] = (_Float16)ax; l[0] = (_Float16)(ax - (float)h[0]);
        h[1] = (_Float16)ay; l[1] = (_Float16)(ay - (float)h[1]);
        h[2] = (_Float16)az; l[2] = (_Float16)(az - (float)h[2]);
        h[3] = (_Float16)aw; l[3] = (_Float16)(aw - (float)h[3]);
        int chunk = lane >> 1;                       // 16B chunk 0..31
        int off = row * 512 + (((chunk) ^ (row & 7)) << 4) + (lane & 1) * 8;
        *(uint2*)(smem + off)        = *(uint2*)&h;
        *(uint2*)(smem + 8192 + off) = *(uint2*)&l;
    }
    __syncthreads();

    // ---- phase 2: M=16 GEMM, no barriers in k-loop ----
    const int r15 = lane & 15, kg = lane >> 4;
    f32x4 acc[4];
    #pragma unroll
    for (int n = 0; n < 4; n++) acc[n] = (f32x4){0.f, 0.f, 0.f, 0.f};

    #pragma unroll
    for (int ks = 0; ks < 8; ks++) {
        int c = ks * 4 + kg;
        int aoff = r15 * 512 + (((c) ^ (r15 & 7)) << 4);
        f16x8 ah = *(const f16x8*)(smem + aoff);
        f16x8 al = *(const f16x8*)(smem + 8192 + aoff);
        #pragma unroll
        for (int n = 0; n < 4; n++) {
            int C = wid * 64 + n * 16 + r15;
            f16x8 bh = *(const f16x8*)(Bh + (size_t)C * CH + ks * 32 + kg * 8);
            f16x8 bl = *(const f16x8*)(Bl + (size_t)C * CH + ks * 32 + kg * 8);
            acc[n] = __builtin_amdgcn_mfma_f32_16x16x32_f16(ah, bh, acc[n], 0, 0, 0);
            acc[n] = __builtin_amdgcn_mfma_f32_16x16x32_f16(ah, bl, acc[n], 0, 0, 0);
            acc[n] = __builtin_amdgcn_mfma_f32_16x16x32_f16(al, bh, acc[n], 0, 0, 0);
        }
    }
    __syncthreads();   // all Y reads complete before LDS reuse

    // ---- phase 3: bias(+gelu), absmax, fp32 tile -> swizzled LDS [16][256] ----
    float mx = 0.f;
    #pragma unroll
    for (int n = 0; n < 4; n++) {
        int col = wid * 64 + n * 16 + r15;
        float b = bias[col];
        int c4 = col >> 2;
        #pragma unroll
        for (int r = 0; r < 4; r++) {
            float v = acc[n][r] + b;
            if (MODE == 0) v = gelu_f(v);
            mx = fmaxf(mx, fabsf(v));
            int rr = kg * 4 + r;                    // row 0..15 (C/D layout)
            *(float*)(smem + rr * 1024 + (((c4) ^ (rr & 7)) << 4) + (col & 3) * 4) = v;
        }
    }
    #pragma unroll
    for (int off = 32; off > 0; off >>= 1)
        mx = fmaxf(mx, __shfl_xor(mx, off));
    if (lane == 0) red[wid] = mx;
    __syncthreads();

    // ---- output: quantize (MODE 0) or fp32 (MODE 1) ----
    int row = tid >> 4;            // 0..15
    int jj = tid & 15;             // 16 threads/row, 16 ch each
    int grow = m0 + row;
    if (MODE == 0) {
        float tmax = fmaxf(fmaxf(red[0], red[1]), fmaxf(red[2], red[3]));
        float inv = (tmax > 0.f) ? (32767.0f / tmax) : 0.f;
        if (grow < N) {
            unsigned pk[8];
            #pragma unroll
            for (int cc = 0; cc < 4; cc++) {
                int c4 = jj * 4 + cc;
                f32x4 v = *(const f32x4*)(smem + row * 1024 + (((c4) ^ (row & 7)) << 4));
                int q0 = __float2int_rn(v[0] * inv);
                int q1 = __float2int_rn(v[1] * inv);
                int q2 = __float2int_rn(v[2] * inv);
                int q3 = __float2int_rn(v[3] * inv);
                pk[cc * 2 + 0] = (q0 & 0xFFFF) | (q1 << 16);
                pk[cc * 2 + 1] = (q2 & 0xFFFF) | (q3 << 16);
            }
            uint8_t* dst = Xout + (size_t)grow * 512 + (size_t)jj * 32;
            *(uint4*)dst = make_uint4(pk[0], pk[1], pk[2], pk[3]);
            *(uint4*)(dst + 16) = make_uint4(pk[4], pk[5], pk[6], pk[7]);
        }
        if (tid < 16 && m0 + tid < N) {
            float tm = fmaxf(fmaxf(red[0], red[1]), fmaxf(red[2], red[3]));
            sout[m0 + tid] = tm * (1.0f / 32767.0f);
        }
    } else {
        if (grow < N) {
            #pragma unroll
            for (int cc = 0; cc < 4; cc++) {
                int c4 = jj * 4 + cc;
                f32x4 v = *(const f32x4*)(smem + row * 1024 + (((c4) ^ (row & 7)) << 4));
                *(f32x4*)(out + (size_t)grow * CH + c4 * 4) = v;
            }
        }
    }
}

// ---------------- launcher ----------------

extern "C" void kernel_launch(void* const* d_in, const int* in_sizes, int n_in,
                              void* d_out, int out_size, void* d_ws, size_t ws_size,
                              hipStream_t stream) {
    const float* x  = (const float*)d_in[0];
    const void*  ei = d_in[1];
    const float* W1 = (const float*)d_in[3]; const float* b1 = (const float*)d_in[4];
    const float* W2 = (const float*)d_in[5]; const float* b2 = (const float*)d_in[6];
    const float* W3 = (const float*)d_in[7]; const float* b3 = (const float*)d_in[8];

    int N = in_sizes[0] / CH;
    int E = in_sizes[1] / 2;
    float* out = (float*)d_out;

    char* ws = (char*)d_ws;
    auto take = [&](size_t bytes) {
        char* p = ws;
        ws += (bytes + 15) & ~(size_t)15;
        return p;
    };
    uint8_t*  Xa     = (uint8_t*) take((size_t)N * 512);
    uint8_t*  Xb     = (uint8_t*) take((size_t)N * 512);
    float*    sa     = (float*)   take((size_t)N * sizeof(float));
    float*    sb     = (float*)   take((size_t)N * sizeof(float));
    int*      deg    = (int*)     take((size_t)N * sizeof(int));
    float*    dis    = (float*)   take((size_t)N * sizeof(float));
    int*      rowptr = (int*)     take((size_t)(N + 1) * sizeof(int));
    int*      cnt    = (int*)     take((size_t)N * sizeof(int));
    int*      part   = (int*)     take(4096);
    int*      flag   = (int*)     take(16);
    int2*     epack  = (int2*)    take((size_t)E * sizeof(int2));
    _Float16* Wh1    = (_Float16*)take((size_t)CH * CH * 2);
    _Float16* Wl1    = (_Float16*)take((size_t)CH * CH * 2);
    _Float16* Wh2    = (_Float16*)take((size_t)CH * CH * 2);
    _Float16* Wl2    = (_Float16*)take((size_t)CH * CH * 2);
    _Float16* Wh3    = (_Float16*)take((size_t)CH * CH * 2);
    _Float16* Wl3    = (_Float16*)take((size_t)CH * CH * 2);

    hipMemsetAsync(deg, 0, (size_t)N * sizeof(int), stream);
    hipMemsetAsync(cnt, 0, (size_t)N * sizeof(int), stream);

    int eb = (E + 255) / 256;
    int nb = (N + 255) / 256;

    k_detect<<<1, 64, 0, stream>>>(ei, flag, E);
    k_deg<<<eb, 256, 0, stream>>>(ei, flag, deg, E);
    k_dis<<<nb, 256, 0, stream>>>(deg, dis, N);
    k_scan_block<<<nb, 256, 0, stream>>>(deg, rowptr, part, N);
    k_scan_partial<<<1, 256, 0, stream>>>(part, nb);
    k_add_off<<<nb, 256, 0, stream>>>(rowptr, part, N, E);
    k_scatter<<<eb, 256, 0, stream>>>(ei, flag, dis, rowptr, cnt, epack, E);

    k_split_w<<<CH, CH, 0, stream>>>(W1, Wh1, Wl1);
    k_split_w<<<CH, CH, 0, stream>>>(W2, Wh2, Wl2);
    k_split_w<<<CH, CH, 0, stream>>>(W3, Wh3, Wl3);

    dim3 qgrid((N + 3) / 4);
    dim3 qblock(64, 4);
    k_quant_x<<<qgrid, qblock, 0, stream>>>(x, Xa, sa, N);

    dim3 lgrid((N + 15) / 16);

    // layer 1: Xa -> Xb
    k_layer<0><<<lgrid, 256, 0, stream>>>(Xa, sa, Wh1, Wl1, dis, rowptr, epack, b1,
                                          Xb, sb, out, N);
    // layer 2: Xb -> Xa
    k_layer<0><<<lgrid, 256, 0, stream>>>(Xb, sb, Wh2, Wl2, dis, rowptr, epack, b2,
                                          Xa, sa, out, N);
    // layer 3: Xa -> out (fp32, no gelu)
    k_layer<1><<<lgrid, 256, 0, stream>>>(Xa, sa, Wh3, Wl3, dis, rowptr, epack, b3,
                                          Xb, sb, out, N);
}

// Round 12
// 433.153 us; speedup vs baseline: 1.5801x; 1.3600x over previous
//
#include <hip/hip_runtime.h>
#include <cstdint>
#include <cstddef>

#define CH 256      // all layers are 256-channel

typedef _Float16 f16x8 __attribute__((ext_vector_type(8)));
typedef _Float16 f16x4 __attribute__((ext_vector_type(4)));
typedef float f32x4 __attribute__((ext_vector_type(4)));
typedef short short8 __attribute__((ext_vector_type(8)));

#define GLOB(x) ((const __attribute__((address_space(1))) void*)(x))
#define LDSP(x) ((__attribute__((address_space(3))) void*)(x))

// ---------------- helpers ----------------

__device__ __forceinline__ int ld_idx(const void* p, long long i, int w64) {
    if (w64) return (int)((const long long*)p)[i];
    return ((const int*)p)[i];
}

__device__ __forceinline__ float gelu_f(float x) {
    float x3 = x * x * x;
    float t = tanhf(0.7978845608028654f * (x + 0.044715f * x3));
    return 0.5f * x * (1.0f + t);
}

// ---------------- preprocessing ----------------

__global__ void k_detect(const void* __restrict__ ei, int* __restrict__ flag, int E) {
    int l = threadIdx.x;  // 0..63
    long long k = ((long long)l * (long long)(E - 1)) / 63;
    int w = ((const int*)ei)[2 * k + 1];
    unsigned long long vote = __ballot(w == 0);
    if (l == 0) *flag = (vote == ~0ULL) ? 1 : 0;
}

__global__ void k_deg(const void* __restrict__ ei, const int* __restrict__ flag,
                      int* __restrict__ deg, int E) {
    int e = blockIdx.x * blockDim.x + threadIdx.x;
    if (e >= E) return;
    int w64 = *flag;
    int d = ld_idx(ei, (long long)E + e, w64);
    atomicAdd(&deg[d], 1);
}

__global__ void k_dis(const int* __restrict__ deg, float* __restrict__ dis, int N) {
    int n = blockIdx.x * blockDim.x + threadIdx.x;
    if (n >= N) return;
    dis[n] = 1.0f / sqrtf((float)(deg[n] + 1));
}

__global__ void k_scan_block(const int* __restrict__ deg, int* __restrict__ rowptr,
                             int* __restrict__ partial, int N) {
    __shared__ int s[256];
    int gid = blockIdx.x * 256 + threadIdx.x;
    int v = (gid < N) ? deg[gid] : 0;
    s[threadIdx.x] = v;
    __syncthreads();
    for (int off = 1; off < 256; off <<= 1) {
        int t = (threadIdx.x >= off) ? s[threadIdx.x - off] : 0;
        __syncthreads();
        s[threadIdx.x] += t;
        __syncthreads();
    }
    if (gid < N) rowptr[gid] = s[threadIdx.x] - v;
    if (threadIdx.x == 255) partial[blockIdx.x] = s[255];
}

__global__ void k_scan_partial(int* __restrict__ partial, int nb) {
    __shared__ int s[256];
    int i = threadIdx.x;
    int v = (i < nb) ? partial[i] : 0;
    s[i] = v;
    __syncthreads();
    for (int off = 1; off < 256; off <<= 1) {
        int t = (i >= off) ? s[i - off] : 0;
        __syncthreads();
        s[i] += t;
        __syncthreads();
    }
    if (i < nb) partial[i] = s[i] - v;
}

__global__ void k_add_off(int* __restrict__ rowptr, const int* __restrict__ partial,
                          int N, int E) {
    int gid = blockIdx.x * 256 + threadIdx.x;
    if (gid < N) rowptr[gid] += partial[blockIdx.x];
    if (gid == 0) rowptr[N] = E;
}

__global__ void k_scatter(const void* __restrict__ ei, const int* __restrict__ flag,
                          const float* __restrict__ dis, const int* __restrict__ rowptr,
                          int* __restrict__ cnt, int2* __restrict__ epack, int E) {
    int e = blockIdx.x * blockDim.x + threadIdx.x;
    if (e >= E) return;
    int w64 = *flag;
    int s = ld_idx(ei, e, w64);
    int d = ld_idx(ei, (long long)E + e, w64);
    int pos = rowptr[d] + atomicAdd(&cnt[d], 1);
    epack[pos] = make_int2(s, __float_as_int(dis[s] * dis[d]));
}

// ---------------- weight split: W[k][c] fp32 -> Wt hi/lo fp16 [c][k] ----------------

__global__ void k_split_w(const float* __restrict__ W, _Float16* __restrict__ Wh,
                          _Float16* __restrict__ Wl) {
    int k = threadIdx.x;   // 0..255
    int c = blockIdx.x;    // 0..255
    float v = W[k * CH + c];
    _Float16 h = (_Float16)v;
    Wh[c * CH + k] = h;
    Wl[c * CH + k] = (_Float16)(v - (float)h);
}

// ---------------- input quantize: fp32 x -> int16 rows + per-node scale ----------------

__global__ __launch_bounds__(256) void k_quant_x(const float* __restrict__ x,
                                                 uint8_t* __restrict__ Xout,
                                                 float* __restrict__ sout, int N) {
    int node = blockIdx.x * 4 + threadIdx.y;
    if (node >= N) return;
    int lane = threadIdx.x;
    float4 v = ((const float4*)(x + (size_t)node * CH))[lane];
    float mx = fmaxf(fmaxf(fabsf(v.x), fabsf(v.y)), fmaxf(fabsf(v.z), fabsf(v.w)));
    #pragma unroll
    for (int off = 32; off > 0; off >>= 1)
        mx = fmaxf(mx, __shfl_xor(mx, off));
    float inv = (mx > 0.f) ? (32767.0f / mx) : 0.f;
    short4 q;
    q.x = (short)__float2int_rn(v.x * inv);
    q.y = (short)__float2int_rn(v.y * inv);
    q.z = (short)__float2int_rn(v.z * inv);
    q.w = (short)__float2int_rn(v.w * inv);
    *(short4*)(Xout + (size_t)node * 512 + (size_t)lane * 8) = q;
    if (lane == 0) sout[node] = mx * (1.0f / 32767.0f);
}

// ---------------- fp16x2 split GEMM (int16 A), int16-quantized output ----------------
// H16[M][512B] = quant16(dequant(X16,sx) @ W); W pre-split+transposed (Bh/Bl [c][k]).
// A staged int16 to LDS (512 chunks), dequant+hi/lo split in registers (row-uniform scale).
// Block: 128x128 output, 4 waves of 64x64, MFMA 16x16x32_f16, K-step 32.
// Per-(tile,half) scale in scales[node*2+half].

#define GM 128
#define GN 128
#define GK 32

__global__ __launch_bounds__(256, 2)
void k_gemm16(const uint8_t* __restrict__ X16, const float* __restrict__ sx,
              const _Float16* __restrict__ Bh, const _Float16* __restrict__ Bl,
              uint8_t* __restrict__ H16, float* __restrict__ scales, int M) {
    __shared__ __align__(16) char smem[65536];
    short*    lA16 = (short*)smem;             // [2][128*32] int16 = 16 KB
    _Float16* lB   = (_Float16*)(smem + 16384); // [2][2][128*32] f16 = 32 KB (+16 KB spare)

    const int tid  = threadIdx.x;
    const int lane = tid & 63;
    const int wid  = tid >> 6;
    const int m0   = blockIdx.x * GM;
    const int n0   = blockIdx.y * GN;
    const int wm   = wid >> 1, wn = wid & 1;
    const int r15  = lane & 15, kg = lane >> 4;

    // stage one K-step tile: A = 512 chunks(16B), Bh = 512, Bl = 512 -> 24 calls, 6/wave
    auto stage = [&](int buf, int k0) {
        #pragma unroll
        for (int c = 0; c < 6; c++) {
            int call = wid * 6 + c;                 // wave-uniform 0..23
            if (call < 8) {                         // A int16: 128 rows x 4 chunks
                int L = call * 64 + lane;           // 0..511
                int row = L >> 2, ch = L & 3;
                int sch = ch ^ ((row >> 1) & 3);
                int gr = m0 + row; gr = (gr < M) ? gr : (M - 1);
                const uint8_t* g = X16 + (size_t)gr * 512 + (size_t)k0 * 2 + (sch << 4);
                __builtin_amdgcn_global_load_lds(GLOB(g), LDSP(&lA16[buf * 4096 + L * 8]), 16, 0, 0);
            } else if (call < 16) {                 // B hi: 128 rows x 4 chunks
                int cc = call - 8;
                int L = cc * 64 + lane;
                int row = L >> 2, ch = L & 3;
                const _Float16* g = Bh + (size_t)(n0 + row) * CH + k0 + ((ch ^ ((row >> 1) & 3)) << 3);
                __builtin_amdgcn_global_load_lds(GLOB(g), LDSP(&lB[buf * 8192 + cc * 512]), 16, 0, 0);
            } else {                                // B lo
                int cc = call - 16;
                int L = cc * 64 + lane;
                int row = L >> 2, ch = L & 3;
                const _Float16* g = Bl + (size_t)(n0 + row) * CH + k0 + ((ch ^ ((row >> 1) & 3)) << 3);
                __builtin_amdgcn_global_load_lds(GLOB(g), LDSP(&lB[buf * 8192 + 4096 + cc * 512]), 16, 0, 0);
            }
        }
    };

    // hoist per-row scales (row-uniform within each A fragment)
    float sA[4];
    #pragma unroll
    for (int i = 0; i < 4; i++) {
        int gr = m0 + wm * 64 + i * 16 + r15;
        sA[i] = sx[(gr < M) ? gr : (M - 1)];
    }

    f32x4 acc[4][4];
    #pragma unroll
    for (int i = 0; i < 4; i++)
        #pragma unroll
        for (int n = 0; n < 4; n++)
            acc[i][n] = (f32x4){0.f, 0.f, 0.f, 0.f};

    stage(0, 0);
    __syncthreads();

    for (int ks = 0; ks < 8; ks++) {
        int cur = ks & 1;
        if (ks < 7) stage(cur ^ 1, (ks + 1) * GK);

        f16x8 ah[4], al[4], bh[4], bl[4];
        #pragma unroll
        for (int i = 0; i < 4; i++) {
            int R = wm * 64 + i * 16 + r15;
            int p = kg ^ ((R >> 1) & 3);
            short8 q = *(const short8*)&lA16[cur * 4096 + R * 32 + p * 8];
            float s = sA[i];
            #pragma unroll
            for (int j = 0; j < 8; j++) {
                float v = s * (float)q[j];
                _Float16 h = (_Float16)v;
                ah[i][j] = h;
                al[i][j] = (_Float16)(v - (float)h);
            }
        }
        #pragma unroll
        for (int n = 0; n < 4; n++) {
            int C = wn * 64 + n * 16 + r15;
            int p = kg ^ ((C >> 1) & 3);
            bh[n] = *(const f16x8*)&lB[cur * 8192 + C * GK + p * 8];
            bl[n] = *(const f16x8*)&lB[cur * 8192 + 4096 + C * GK + p * 8];
        }
        #pragma unroll
        for (int i = 0; i < 4; i++)
            #pragma unroll
            for (int n = 0; n < 4; n++) {
                acc[i][n] = __builtin_amdgcn_mfma_f32_16x16x32_f16(ah[i], bh[n], acc[i][n], 0, 0, 0);
                acc[i][n] = __builtin_amdgcn_mfma_f32_16x16x32_f16(ah[i], bl[n], acc[i][n], 0, 0, 0);
                acc[i][n] = __builtin_amdgcn_mfma_f32_16x16x32_f16(al[i], bh[n], acc[i][n], 0, 0, 0);
            }
        __syncthreads();
    }

    // ---- epilogue: tile absmax -> scale, transpose via LDS, int16 store ----
    float mx = 0.f;
    #pragma unroll
    for (int i = 0; i < 4; i++)
        #pragma unroll
        for (int n = 0; n < 4; n++)
            #pragma unroll
            for (int r = 0; r < 4; r++)
                mx = fmaxf(mx, fabsf(acc[i][n][r]));
    #pragma unroll
    for (int off = 32; off > 0; off >>= 1)
        mx = fmaxf(mx, __shfl_xor(mx, off));
    if (lane == 0) ((float*)smem)[wid] = mx;
    __syncthreads();
    float tmax = fmaxf(fmaxf(((float*)smem)[0], ((float*)smem)[1]),
                       fmaxf(((float*)smem)[2], ((float*)smem)[3]));
    float scl = tmax * (1.0f / 32767.0f);
    float inv = (tmax > 0.f) ? (32767.0f / tmax) : 0.f;
    __syncthreads();

    float* ep = (float*)smem + wid * 4096;   // 64x64 fp32 tile per wave (16 KB)
    #pragma unroll
    for (int i = 0; i < 4; i++)
        #pragma unroll
        for (int n = 0; n < 4; n++)
            #pragma unroll
            for (int r = 0; r < 4; r++)
                ep[(i * 16 + kg * 4 + r) * 64 + n * 16 + r15] = acc[i][n][r];
    __syncthreads();

    int q = lane & 15;            // channel quad within tile
    int rsub = lane >> 4;         // row sub-index
    #pragma unroll
    for (int p = 0; p < 16; p++) {
        int lrow = p * 4 + rsub;                    // 0..63
        int grow = m0 + wm * 64 + lrow;
        if (grow < M) {
            int q0 = __float2int_rn(ep[lrow * 64 + q * 4 + 0] * inv);
            int q1 = __float2int_rn(ep[lrow * 64 + q * 4 + 1] * inv);
            int q2 = __float2int_rn(ep[lrow * 64 + q * 4 + 2] * inv);
            int q3 = __float2int_rn(ep[lrow * 64 + q * 4 + 3] * inv);
            uint2 d;
            d.x = (q0 & 0xFFFF) | (q1 << 16);
            d.y = (q2 & 0xFFFF) | (q3 << 16);
            int col = n0 + wn * 64 + q * 4;
            *(uint2*)(H16 + (size_t)grow * 512 + (size_t)col * 2) = d;
        }
    }

    if (tid < GM && m0 + tid < M) scales[(size_t)(m0 + tid) * 2 + (n0 >> 7)] = scl;
}

// ---------------- sparse aggregation (gather-CSR over int16 H) ----------------
// out[n] = dis[n]^2*h[n] + sum_e norm_e * h[src_e] (+bias)
// MODE 0: gelu -> per-node absmax -> int16 quantize to Xout + sxout (layers 1,2)
// MODE 1: fp32 store to out (layer 3, no gelu)

template <int MODE>
__global__ __launch_bounds__(256) void k_agg(const uint8_t* __restrict__ H16,
                                             const float* __restrict__ scales,
                                             const float* __restrict__ dis,
                                             const int* __restrict__ rowptr,
                                             const int2* __restrict__ epack,
                                             const float* __restrict__ bias,
                                             float* __restrict__ out,
                                             uint8_t* __restrict__ Xout,
                                             float* __restrict__ sxout, int N) {
    int node = blockIdx.x * 4 + threadIdx.y;
    if (node >= N) return;
    int lane = threadIdx.x;  // 0..63
    int half = lane >> 5;    // which 128-ch half this lane's 4 channels live in
    float d = dis[node];
    short4 hv = *(const short4*)(H16 + (size_t)node * 512 + (size_t)lane * 8);
    float wself = d * d * scales[(size_t)node * 2 + half];
    float ax = wself * (float)hv.x, ay = wself * (float)hv.y;
    float az = wself * (float)hv.z, aw = wself * (float)hv.w;
    int s = rowptr[node], e = rowptr[node + 1];
    int j = s;
    for (; j + 8 <= e; j += 8) {
        int2 p[8];
        #pragma unroll
        for (int t = 0; t < 8; t++) p[t] = epack[j + t];
        short4 v[8];
        float sc[8];
        #pragma unroll
        for (int t = 0; t < 8; t++) {
            v[t] = *(const short4*)(H16 + (size_t)p[t].x * 512 + (size_t)lane * 8);
            sc[t] = scales[(size_t)p[t].x * 2 + half];
        }
        #pragma unroll
        for (int t = 0; t < 8; t++) {
            float wn = __int_as_float(p[t].y) * sc[t];
            ax += wn * (float)v[t].x; ay += wn * (float)v[t].y;
            az += wn * (float)v[t].z; aw += wn * (float)v[t].w;
        }
    }
    for (; j < e; j++) {
        int2 p = epack[j];
        float wn = __int_as_float(p.y) * scales[(size_t)p.x * 2 + half];
        short4 v = *(const short4*)(H16 + (size_t)p.x * 512 + (size_t)lane * 8);
        ax += wn * (float)v.x; ay += wn * (float)v.y;
        az += wn * (float)v.z; aw += wn * (float)v.w;
    }
    float4 b = ((const float4*)bias)[lane];
    ax += b.x; ay += b.y; az += b.z; aw += b.w;
    if (MODE == 0) {
        ax = gelu_f(ax); ay = gelu_f(ay); az = gelu_f(az); aw = gelu_f(aw);
        float mx = fmaxf(fmaxf(fabsf(ax), fabsf(ay)), fmaxf(fabsf(az), fabsf(aw)));
        #pragma unroll
        for (int off = 32; off > 0; off >>= 1)
            mx = fmaxf(mx, __shfl_xor(mx, off));
        float inv = (mx > 0.f) ? (32767.0f / mx) : 0.f;
        short4 q;
        q.x = (short)__float2int_rn(ax * inv);
        q.y = (short)__float2int_rn(ay * inv);
        q.z = (short)__float2int_rn(az * inv);
        q.w = (short)__float2int_rn(aw * inv);
        *(short4*)(Xout + (size_t)node * 512 + (size_t)lane * 8) = q;
        if (lane == 0) sxout[node] = mx * (1.0f / 32767.0f);
    } else {
        ((float4*)(out + (size_t)node * CH))[lane] = make_float4(ax, ay, az, aw);
    }
}

// ---------------- launcher ----------------

extern "C" void kernel_launch(void* const* d_in, const int* in_sizes, int n_in,
                              void* d_out, int out_size, void* d_ws, size_t ws_size,
                              hipStream_t stream) {
    const float* x  = (const float*)d_in[0];
    const void*  ei = d_in[1];
    const float* W1 = (const float*)d_in[3]; const float* b1 = (const float*)d_in[4];
    const float* W2 = (const float*)d_in[5]; const float* b2 = (const float*)d_in[6];
    const float* W3 = (const float*)d_in[7]; const float* b3 = (const float*)d_in[8];

    int N = in_sizes[0] / CH;
    int E = in_sizes[1] / 2;
    float* out = (float*)d_out;

    char* ws = (char*)d_ws;
    auto take = [&](size_t bytes) {
        char* p = ws;
        ws += (bytes + 15) & ~(size_t)15;
        return p;
    };
    uint8_t*  H16    = (uint8_t*) take((size_t)N * 512);
    uint8_t*  Xa     = (uint8_t*) take((size_t)N * 512);
    uint8_t*  Xb     = (uint8_t*) take((size_t)N * 512);
    float*    hscl   = (float*)   take((size_t)N * 2 * sizeof(float));
    float*    sxa    = (float*)   take((size_t)N * sizeof(float));
    float*    sxb    = (float*)   take((size_t)N * sizeof(float));
    int*      deg    = (int*)     take((size_t)N * sizeof(int));
    float*    dis    = (float*)   take((size_t)N * sizeof(float));
    int*      rowptr = (int*)     take((size_t)(N + 1) * sizeof(int));
    int*      cnt    = (int*)     take((size_t)N * sizeof(int));
    int*      part   = (int*)     take(4096);
    int*      flag   = (int*)     take(16);
    int2*     epack  = (int2*)    take((size_t)E * sizeof(int2));
    _Float16* Wh1    = (_Float16*)take((size_t)CH * CH * 2);
    _Float16* Wl1    = (_Float16*)take((size_t)CH * CH * 2);
    _Float16* Wh2    = (_Float16*)take((size_t)CH * CH * 2);
    _Float16* Wl2    = (_Float16*)take((size_t)CH * CH * 2);
    _Float16* Wh3    = (_Float16*)take((size_t)CH * CH * 2);
    _Float16* Wl3    = (_Float16*)take((size_t)CH * CH * 2);

    hipMemsetAsync(deg, 0, (size_t)N * sizeof(int), stream);
    hipMemsetAsync(cnt, 0, (size_t)N * sizeof(int), stream);

    int eb = (E + 255) / 256;
    int nb = (N + 255) / 256;

    k_detect<<<1, 64, 0, stream>>>(ei, flag, E);
    k_deg<<<eb, 256, 0, stream>>>(ei, flag, deg, E);
    k_dis<<<nb, 256, 0, stream>>>(deg, dis, N);
    k_scan_block<<<nb, 256, 0, stream>>>(deg, rowptr, part, N);
    k_scan_partial<<<1, 256, 0, stream>>>(part, nb);
    k_add_off<<<nb, 256, 0, stream>>>(rowptr, part, N, E);
    k_scatter<<<eb, 256, 0, stream>>>(ei, flag, dis, rowptr, cnt, epack, E);

    k_split_w<<<CH, CH, 0, stream>>>(W1, Wh1, Wl1);
    k_split_w<<<CH, CH, 0, stream>>>(W2, Wh2, Wl2);
    k_split_w<<<CH, CH, 0, stream>>>(W3, Wh3, Wl3);

    dim3 qgrid((N + 3) / 4);
    dim3 qblock(64, 4);
    k_quant_x<<<qgrid, qblock, 0, stream>>>(x, Xa, sxa, N);

    dim3 ggrid((N + GM - 1) / GM, CH / GN);
    dim3 agrid((N + 3) / 4);
    dim3 ablock(64, 4);

    // layer 1: Xa -> H16 -> Xb
    k_gemm16<<<ggrid, 256, 0, stream>>>(Xa, sxa, Wh1, Wl1, H16, hscl, N);
    k_agg<0><<<agrid, ablock, 0, stream>>>(H16, hscl, dis, rowptr, epack, b1, out, Xb, sxb, N);
    // layer 2: Xb -> H16 -> Xa
    k_gemm16<<<ggrid, 256, 0, stream>>>(Xb, sxb, Wh2, Wl2, H16, hscl, N);
    k_agg<0><<<agrid, ablock, 0, stream>>>(H16, hscl, dis, rowptr, epack, b2, out, Xa, sxa, N);
    // layer 3: Xa -> H16 -> out (fp32, no gelu)
    k_gemm16<<<ggrid, 256, 0, stream>>>(Xa, sxa, Wh3, Wl3, H16, hscl, N);
    k_agg<1><<<agrid, ablock, 0, stream>>>(H16, hscl, dis, rowptr, epack, b3, out, Xb, sxb, N);
}

// Round 13
// 413.582 us; speedup vs baseline: 1.6549x; 1.0473x over previous
//
#include <hip/hip_runtime.h>
#include <cstdint>
#include <cstddef>

#define CH 256      // all layers are 256-channel

typedef _Float16 f16x8 __attribute__((ext_vector_type(8)));
typedef _Float16 f16x4 __attribute__((ext_vector_type(4)));
typedef float f32x4 __attribute__((ext_vector_type(4)));
typedef short short8 __attribute__((ext_vector_type(8)));

#define GLOB(x) ((const __attribute__((address_space(1))) void*)(x))
#define LDSP(x) ((__attribute__((address_space(3))) void*)(x))

// ---------------- helpers ----------------

__device__ __forceinline__ int ld_idx(const void* p, long long i, int w64) {
    if (w64) return (int)((const long long*)p)[i];
    return ((const int*)p)[i];
}

__device__ __forceinline__ float gelu_f(float x) {
    float x3 = x * x * x;
    float t = tanhf(0.7978845608028654f * (x + 0.044715f * x3));
    return 0.5f * x * (1.0f + t);
}

// ---------------- preprocessing ----------------

__global__ void k_detect(const void* __restrict__ ei, int* __restrict__ flag, int E) {
    int l = threadIdx.x;  // 0..63
    long long k = ((long long)l * (long long)(E - 1)) / 63;
    int w = ((const int*)ei)[2 * k + 1];
    unsigned long long vote = __ballot(w == 0);
    if (l == 0) *flag = (vote == ~0ULL) ? 1 : 0;
}

__global__ void k_deg(const void* __restrict__ ei, const int* __restrict__ flag,
                      int* __restrict__ deg, int E) {
    int e = blockIdx.x * blockDim.x + threadIdx.x;
    if (e >= E) return;
    int w64 = *flag;
    int d = ld_idx(ei, (long long)E + e, w64);
    atomicAdd(&deg[d], 1);
}

__global__ void k_dis(const int* __restrict__ deg, float* __restrict__ dis, int N) {
    int n = blockIdx.x * blockDim.x + threadIdx.x;
    if (n >= N) return;
    dis[n] = 1.0f / sqrtf((float)(deg[n] + 1));
}

__global__ void k_scan_block(const int* __restrict__ deg, int* __restrict__ rowptr,
                             int* __restrict__ partial, int N) {
    __shared__ int s[256];
    int gid = blockIdx.x * 256 + threadIdx.x;
    int v = (gid < N) ? deg[gid] : 0;
    s[threadIdx.x] = v;
    __syncthreads();
    for (int off = 1; off < 256; off <<= 1) {
        int t = (threadIdx.x >= off) ? s[threadIdx.x - off] : 0;
        __syncthreads();
        s[threadIdx.x] += t;
        __syncthreads();
    }
    if (gid < N) rowptr[gid] = s[threadIdx.x] - v;
    if (threadIdx.x == 255) partial[blockIdx.x] = s[255];
}

__global__ void k_scan_partial(int* __restrict__ partial, int nb) {
    __shared__ int s[256];
    int i = threadIdx.x;
    int v = (i < nb) ? partial[i] : 0;
    s[i] = v;
    __syncthreads();
    for (int off = 1; off < 256; off <<= 1) {
        int t = (i >= off) ? s[i - off] : 0;
        __syncthreads();
        s[i] += t;
        __syncthreads();
    }
    if (i < nb) partial[i] = s[i] - v;
}

__global__ void k_add_off(int* __restrict__ rowptr, const int* __restrict__ partial,
                          int N, int E) {
    int gid = blockIdx.x * 256 + threadIdx.x;
    if (gid < N) rowptr[gid] += partial[blockIdx.x];
    if (gid == 0) rowptr[N] = E;
}

__global__ void k_scatter(const void* __restrict__ ei, const int* __restrict__ flag,
                          const float* __restrict__ dis, const int* __restrict__ rowptr,
                          int* __restrict__ cnt, int2* __restrict__ epack, int E) {
    int e = blockIdx.x * blockDim.x + threadIdx.x;
    if (e >= E) return;
    int w64 = *flag;
    int s = ld_idx(ei, e, w64);
    int d = ld_idx(ei, (long long)E + e, w64);
    int pos = rowptr[d] + atomicAdd(&cnt[d], 1);
    epack[pos] = make_int2(s, __float_as_int(dis[s] * dis[d]));
}

// ---------------- weight split: W[k][c] fp32 -> Wt hi/lo fp16 [c][k] ----------------

__global__ void k_split_w(const float* __restrict__ W, _Float16* __restrict__ Wh,
                          _Float16* __restrict__ Wl) {
    int k = threadIdx.x;   // 0..255
    int c = blockIdx.x;    // 0..255
    float v = W[k * CH + c];
    _Float16 h = (_Float16)v;
    Wh[c * CH + k] = h;
    Wl[c * CH + k] = (_Float16)(v - (float)h);
}

// ---------------- input quantize: fp32 x -> int16 rows + per-node scale ----------------

__global__ __launch_bounds__(256) void k_quant_x(const float* __restrict__ x,
                                                 uint8_t* __restrict__ Xout,
                                                 float* __restrict__ sout, int N) {
    int node = blockIdx.x * 4 + threadIdx.y;
    if (node >= N) return;
    int lane = threadIdx.x;
    float4 v = ((const float4*)(x + (size_t)node * CH))[lane];
    float mx = fmaxf(fmaxf(fabsf(v.x), fabsf(v.y)), fmaxf(fabsf(v.z), fabsf(v.w)));
    #pragma unroll
    for (int off = 32; off > 0; off >>= 1)
        mx = fmaxf(mx, __shfl_xor(mx, off));
    float inv = (mx > 0.f) ? (32767.0f / mx) : 0.f;
    short4 q;
    q.x = (short)__float2int_rn(v.x * inv);
    q.y = (short)__float2int_rn(v.y * inv);
    q.z = (short)__float2int_rn(v.z * inv);
    q.w = (short)__float2int_rn(v.w * inv);
    *(short4*)(Xout + (size_t)node * 512 + (size_t)lane * 8) = q;
    if (lane == 0) sout[node] = mx * (1.0f / 32767.0f);
}

// ---------------- split GEMM (int16 A as fp16, late scale fold) ----------------
// H16[M][512B] = quant16(s_row * (Aq @ W)); W pre-split+transposed (Bh/Bl [c][k]).
// A staged int16 to LDS; fragments cvt i16->f16 directly (12-bit effective, scale
// folded into the accumulator after the k-loop since it is row-uniform).
// Block: 128x128 output, 4 waves of 64x64, MFMA 16x16x32_f16, K-step 32.
// Per-(tile,half) scale in scales[node*2+half].

#define GM 128
#define GN 128
#define GK 32

__global__ __launch_bounds__(256, 2)
void k_gemm16(const uint8_t* __restrict__ X16, const float* __restrict__ sx,
              const _Float16* __restrict__ Bh, const _Float16* __restrict__ Bl,
              uint8_t* __restrict__ H16, float* __restrict__ scales, int M) {
    __shared__ __align__(16) char smem[65536];
    short*    lA16 = (short*)smem;              // [2][128*32] int16 = 16 KB
    _Float16* lB   = (_Float16*)(smem + 16384); // [2][2][128*32] f16 = 32 KB (+16 KB spare)

    const int tid  = threadIdx.x;
    const int lane = tid & 63;
    const int wid  = tid >> 6;
    const int m0   = blockIdx.x * GM;
    const int n0   = blockIdx.y * GN;
    const int wm   = wid >> 1, wn = wid & 1;
    const int r15  = lane & 15, kg = lane >> 4;

    // stage one K-step tile: A = 512 chunks(16B), Bh = 512, Bl = 512 -> 24 calls, 6/wave
    auto stage = [&](int buf, int k0) {
        #pragma unroll
        for (int c = 0; c < 6; c++) {
            int call = wid * 6 + c;                 // wave-uniform 0..23
            if (call < 8) {                         // A int16: 128 rows x 4 chunks
                int L = call * 64 + lane;           // 0..511
                int row = L >> 2, ch = L & 3;
                int sch = ch ^ ((row >> 1) & 3);
                int gr = m0 + row; gr = (gr < M) ? gr : (M - 1);
                const uint8_t* g = X16 + (size_t)gr * 512 + (size_t)k0 * 2 + (sch << 4);
                __builtin_amdgcn_global_load_lds(GLOB(g), LDSP(&lA16[buf * 4096 + L * 8]), 16, 0, 0);
            } else if (call < 16) {                 // B hi: 128 rows x 4 chunks
                int cc = call - 8;
                int L = cc * 64 + lane;
                int row = L >> 2, ch = L & 3;
                const _Float16* g = Bh + (size_t)(n0 + row) * CH + k0 + ((ch ^ ((row >> 1) & 3)) << 3);
                __builtin_amdgcn_global_load_lds(GLOB(g), LDSP(&lB[buf * 8192 + cc * 512]), 16, 0, 0);
            } else {                                // B lo
                int cc = call - 16;
                int L = cc * 64 + lane;
                int row = L >> 2, ch = L & 3;
                const _Float16* g = Bl + (size_t)(n0 + row) * CH + k0 + ((ch ^ ((row >> 1) & 3)) << 3);
                __builtin_amdgcn_global_load_lds(GLOB(g), LDSP(&lB[buf * 8192 + 4096 + cc * 512]), 16, 0, 0);
            }
        }
    };

    f32x4 acc[4][4];
    #pragma unroll
    for (int i = 0; i < 4; i++)
        #pragma unroll
        for (int n = 0; n < 4; n++)
            acc[i][n] = (f32x4){0.f, 0.f, 0.f, 0.f};

    stage(0, 0);
    __syncthreads();

    for (int ks = 0; ks < 8; ks++) {
        int cur = ks & 1;
        if (ks < 7) stage(cur ^ 1, (ks + 1) * GK);

        f16x8 aq[4], bh[4], bl[4];
        #pragma unroll
        for (int i = 0; i < 4; i++) {
            int R = wm * 64 + i * 16 + r15;
            int p = kg ^ ((R >> 1) & 3);
            short8 q = *(const short8*)&lA16[cur * 4096 + R * 32 + p * 8];
            #pragma unroll
            for (int j = 0; j < 8; j++)
                aq[i][j] = (_Float16)q[j];          // v_cvt_f16_i16; scale folded later
        }
        #pragma unroll
        for (int n = 0; n < 4; n++) {
            int C = wn * 64 + n * 16 + r15;
            int p = kg ^ ((C >> 1) & 3);
            bh[n] = *(const f16x8*)&lB[cur * 8192 + C * GK + p * 8];
            bl[n] = *(const f16x8*)&lB[cur * 8192 + 4096 + C * GK + p * 8];
        }
        #pragma unroll
        for (int i = 0; i < 4; i++)
            #pragma unroll
            for (int n = 0; n < 4; n++) {
                acc[i][n] = __builtin_amdgcn_mfma_f32_16x16x32_f16(aq[i], bh[n], acc[i][n], 0, 0, 0);
                acc[i][n] = __builtin_amdgcn_mfma_f32_16x16x32_f16(aq[i], bl[n], acc[i][n], 0, 0, 0);
            }
        __syncthreads();
    }

    // ---- fold row-uniform input scale into the accumulator ----
    // C/D layout: row = i*16 + kg*4 + r (within wave's 64-row block), col = lane&15 based
    float sC[4][4];
    #pragma unroll
    for (int i = 0; i < 4; i++)
        #pragma unroll
        for (int r = 0; r < 4; r++) {
            int gr = m0 + wm * 64 + i * 16 + kg * 4 + r;
            sC[i][r] = sx[(gr < M) ? gr : (M - 1)];
        }
    #pragma unroll
    for (int i = 0; i < 4; i++)
        #pragma unroll
        for (int n = 0; n < 4; n++)
            #pragma unroll
            for (int r = 0; r < 4; r++)
                acc[i][n][r] *= sC[i][r];

    // ---- epilogue: tile absmax -> scale, transpose via LDS, int16 store ----
    float mx = 0.f;
    #pragma unroll
    for (int i = 0; i < 4; i++)
        #pragma unroll
        for (int n = 0; n < 4; n++)
            #pragma unroll
            for (int r = 0; r < 4; r++)
                mx = fmaxf(mx, fabsf(acc[i][n][r]));
    #pragma unroll
    for (int off = 32; off > 0; off >>= 1)
        mx = fmaxf(mx, __shfl_xor(mx, off));
    if (lane == 0) ((float*)smem)[wid] = mx;
    __syncthreads();
    float tmax = fmaxf(fmaxf(((float*)smem)[0], ((float*)smem)[1]),
                       fmaxf(((float*)smem)[2], ((float*)smem)[3]));
    float scl = tmax * (1.0f / 32767.0f);
    float inv = (tmax > 0.f) ? (32767.0f / tmax) : 0.f;
    __syncthreads();

    float* ep = (float*)smem + wid * 4096;   // 64x64 fp32 tile per wave (16 KB)
    #pragma unroll
    for (int i = 0; i < 4; i++)
        #pragma unroll
        for (int n = 0; n < 4; n++)
            #pragma unroll
            for (int r = 0; r < 4; r++)
                ep[(i * 16 + kg * 4 + r) * 64 + n * 16 + r15] = acc[i][n][r];
    __syncthreads();

    int q = lane & 15;            // channel quad within tile
    int rsub = lane >> 4;         // row sub-index
    #pragma unroll
    for (int p = 0; p < 16; p++) {
        int lrow = p * 4 + rsub;                    // 0..63
        int grow = m0 + wm * 64 + lrow;
        if (grow < M) {
            int q0 = __float2int_rn(ep[lrow * 64 + q * 4 + 0] * inv);
            int q1 = __float2int_rn(ep[lrow * 64 + q * 4 + 1] * inv);
            int q2 = __float2int_rn(ep[lrow * 64 + q * 4 + 2] * inv);
            int q3 = __float2int_rn(ep[lrow * 64 + q * 4 + 3] * inv);
            uint2 d;
            d.x = (q0 & 0xFFFF) | (q1 << 16);
            d.y = (q2 & 0xFFFF) | (q3 << 16);
            int col = n0 + wn * 64 + q * 4;
            *(uint2*)(H16 + (size_t)grow * 512 + (size_t)col * 2) = d;
        }
    }

    if (tid < GM && m0 + tid < M) scales[(size_t)(m0 + tid) * 2 + (n0 >> 7)] = scl;
}

// ---------------- sparse aggregation (gather-CSR over int16 H) ----------------
// out[n] = dis[n]^2*h[n] + sum_e norm_e * h[src_e] (+bias)
// MODE 0: gelu -> per-node absmax -> int16 quantize to Xout + sxout (layers 1,2)
// MODE 1: fp32 store to out (layer 3, no gelu)

template <int MODE>
__global__ __launch_bounds__(256) void k_agg(const uint8_t* __restrict__ H16,
                                             const float* __restrict__ scales,
                                             const float* __restrict__ dis,
                                             const int* __restrict__ rowptr,
                                             const int2* __restrict__ epack,
                                             const float* __restrict__ bias,
                                             float* __restrict__ out,
                                             uint8_t* __restrict__ Xout,
                                             float* __restrict__ sxout, int N) {
    int node = blockIdx.x * 4 + threadIdx.y;
    if (node >= N) return;
    int lane = threadIdx.x;  // 0..63
    int half = lane >> 5;    // which 128-ch half this lane's 4 channels live in
    float d = dis[node];
    short4 hv = *(const short4*)(H16 + (size_t)node * 512 + (size_t)lane * 8);
    float wself = d * d * scales[(size_t)node * 2 + half];
    float ax = wself * (float)hv.x, ay = wself * (float)hv.y;
    float az = wself * (float)hv.z, aw = wself * (float)hv.w;
    int s = rowptr[node], e = rowptr[node + 1];
    int j = s;
    for (; j + 8 <= e; j += 8) {
        int2 p[8];
        #pragma unroll
        for (int t = 0; t < 8; t++) p[t] = epack[j + t];
        short4 v[8];
        float sc[8];
        #pragma unroll
        for (int t = 0; t < 8; t++) {
            v[t] = *(const short4*)(H16 + (size_t)p[t].x * 512 + (size_t)lane * 8);
            sc[t] = scales[(size_t)p[t].x * 2 + half];
        }
        #pragma unroll
        for (int t = 0; t < 8; t++) {
            float wn = __int_as_float(p[t].y) * sc[t];
            ax += wn * (float)v[t].x; ay += wn * (float)v[t].y;
            az += wn * (float)v[t].z; aw += wn * (float)v[t].w;
        }
    }
    for (; j < e; j++) {
        int2 p = epack[j];
        float wn = __int_as_float(p.y) * scales[(size_t)p.x * 2 + half];
        short4 v = *(const short4*)(H16 + (size_t)p.x * 512 + (size_t)lane * 8);
        ax += wn * (float)v.x; ay += wn * (float)v.y;
        az += wn * (float)v.z; aw += wn * (float)v.w;
    }
    float4 b = ((const float4*)bias)[lane];
    ax += b.x; ay += b.y; az += b.z; aw += b.w;
    if (MODE == 0) {
        ax = gelu_f(ax); ay = gelu_f(ay); az = gelu_f(az); aw = gelu_f(aw);
        float mx = fmaxf(fmaxf(fabsf(ax), fabsf(ay)), fmaxf(fabsf(az), fabsf(aw)));
        #pragma unroll
        for (int off = 32; off > 0; off >>= 1)
            mx = fmaxf(mx, __shfl_xor(mx, off));
        float inv = (mx > 0.f) ? (32767.0f / mx) : 0.f;
        short4 q;
        q.x = (short)__float2int_rn(ax * inv);
        q.y = (short)__float2int_rn(ay * inv);
        q.z = (short)__float2int_rn(az * inv);
        q.w = (short)__float2int_rn(aw * inv);
        *(short4*)(Xout + (size_t)node * 512 + (size_t)lane * 8) = q;
        if (lane == 0) sxout[node] = mx * (1.0f / 32767.0f);
    } else {
        ((float4*)(out + (size_t)node * CH))[lane] = make_float4(ax, ay, az, aw);
    }
}

// ---------------- launcher ----------------

extern "C" void kernel_launch(void* const* d_in, const int* in_sizes, int n_in,
                              void* d_out, int out_size, void* d_ws, size_t ws_size,
                              hipStream_t stream) {
    const float* x  = (const float*)d_in[0];
    const void*  ei = d_in[1];
    const float* W1 = (const float*)d_in[3]; const float* b1 = (const float*)d_in[4];
    const float* W2 = (const float*)d_in[5]; const float* b2 = (const float*)d_in[6];
    const float* W3 = (const float*)d_in[7]; const float* b3 = (const float*)d_in[8];

    int N = in_sizes[0] / CH;
    int E = in_sizes[1] / 2;
    float* out = (float*)d_out;

    char* ws = (char*)d_ws;
    auto take = [&](size_t bytes) {
        char* p = ws;
        ws += (bytes + 15) & ~(size_t)15;
        return p;
    };
    uint8_t*  H16    = (uint8_t*) take((size_t)N * 512);
    uint8_t*  Xa     = (uint8_t*) take((size_t)N * 512);
    uint8_t*  Xb     = (uint8_t*) take((size_t)N * 512);
    float*    hscl   = (float*)   take((size_t)N * 2 * sizeof(float));
    float*    sxa    = (float*)   take((size_t)N * sizeof(float));
    float*    sxb    = (float*)   take((size_t)N * sizeof(float));
    int*      deg    = (int*)     take((size_t)N * sizeof(int));
    float*    dis    = (float*)   take((size_t)N * sizeof(float));
    int*      rowptr = (int*)     take((size_t)(N + 1) * sizeof(int));
    int*      cnt    = (int*)     take((size_t)N * sizeof(int));
    int*      part   = (int*)     take(4096);
    int*      flag   = (int*)     take(16);
    int2*     epack  = (int2*)    take((size_t)E * sizeof(int2));
    _Float16* Wh1    = (_Float16*)take((size_t)CH * CH * 2);
    _Float16* Wl1    = (_Float16*)take((size_t)CH * CH * 2);
    _Float16* Wh2    = (_Float16*)take((size_t)CH * CH * 2);
    _Float16* Wl2    = (_Float16*)take((size_t)CH * CH * 2);
    _Float16* Wh3    = (_Float16*)take((size_t)CH * CH * 2);
    _Float16* Wl3    = (_Float16*)take((size_t)CH * CH * 2);

    hipMemsetAsync(deg, 0, (size_t)N * sizeof(int), stream);
    hipMemsetAsync(cnt, 0, (size_t)N * sizeof(int), stream);

    int eb = (E + 255) / 256;
    int nb = (N + 255) / 256;

    k_detect<<<1, 64, 0, stream>>>(ei, flag, E);
    k_deg<<<eb, 256, 0, stream>>>(ei, flag, deg, E);
    k_dis<<<nb, 256, 0, stream>>>(deg, dis, N);
    k_scan_block<<<nb, 256, 0, stream>>>(deg, rowptr, part, N);
    k_scan_partial<<<1, 256, 0, stream>>>(part, nb);
    k_add_off<<<nb, 256, 0, stream>>>(rowptr, part, N, E);
    k_scatter<<<eb, 256, 0, stream>>>(ei, flag, dis, rowptr, cnt, epack, E);

    k_split_w<<<CH, CH, 0, stream>>>(W1, Wh1, Wl1);
    k_split_w<<<CH, CH, 0, stream>>>(W2, Wh2, Wl2);
    k_split_w<<<CH, CH, 0, stream>>>(W3, Wh3, Wl3);

    dim3 qgrid((N + 3) / 4);
    dim3 qblock(64, 4);
    k_quant_x<<<qgrid, qblock, 0, stream>>>(x, Xa, sxa, N);

    dim3 ggrid((N + GM - 1) / GM, CH / GN);
    dim3 agrid((N + 3) / 4);
    dim3 ablock(64, 4);

    // layer 1: Xa -> H16 -> Xb
    k_gemm16<<<ggrid, 256, 0, stream>>>(Xa, sxa, Wh1, Wl1, H16, hscl, N);
    k_agg<0><<<agrid, ablock, 0, stream>>>(H16, hscl, dis, rowptr, epack, b1, out, Xb, sxb, N);
    // layer 2: Xb -> H16 -> Xa
    k_gemm16<<<ggrid, 256, 0, stream>>>(Xb, sxb, Wh2, Wl2, H16, hscl, N);
    k_agg<0><<<agrid, ablock, 0, stream>>>(H16, hscl, dis, rowptr, epack, b2, out, Xa, sxa, N);
    // layer 3: Xa -> H16 -> out (fp32, no gelu)
    k_gemm16<<<ggrid, 256, 0, stream>>>(Xa, sxa, Wh3, Wl3, H16, hscl, N);
    k_agg<1><<<agrid, ablock, 0, stream>>>(H16, hscl, dis, rowptr, epack, b3, out, Xb, sxb, N);
}

// Round 14
// 389.932 us; speedup vs baseline: 1.7553x; 1.0607x over previous
//
#include <hip/hip_runtime.h>
#include <cstdint>
#include <cstddef>

#define CH 256      // all layers are 256-channel

typedef _Float16 f16x8 __attribute__((ext_vector_type(8)));
typedef _Float16 f16x4 __attribute__((ext_vector_type(4)));
typedef float f32x4 __attribute__((ext_vector_type(4)));
typedef short short8 __attribute__((ext_vector_type(8)));

#define GLOB(x) ((const __attribute__((address_space(1))) void*)(x))
#define LDSP(x) ((__attribute__((address_space(3))) void*)(x))

// ---------------- helpers ----------------

__device__ __forceinline__ int ld_idx(const void* p, long long i, int w64) {
    if (w64) return (int)((const long long*)p)[i];
    return ((const int*)p)[i];
}

__device__ __forceinline__ float gelu_f(float x) {
    float x3 = x * x * x;
    float t = tanhf(0.7978845608028654f * (x + 0.044715f * x3));
    return 0.5f * x * (1.0f + t);
}

// ---------------- preprocessing ----------------

__global__ void k_detect(const void* __restrict__ ei, int* __restrict__ flag, int E) {
    int l = threadIdx.x;  // 0..63
    long long k = ((long long)l * (long long)(E - 1)) / 63;
    int w = ((const int*)ei)[2 * k + 1];
    unsigned long long vote = __ballot(w == 0);
    if (l == 0) *flag = (vote == ~0ULL) ? 1 : 0;
}

__global__ void k_deg(const void* __restrict__ ei, const int* __restrict__ flag,
                      int* __restrict__ deg, int E) {
    int e = blockIdx.x * blockDim.x + threadIdx.x;
    if (e >= E) return;
    int w64 = *flag;
    int d = ld_idx(ei, (long long)E + e, w64);
    atomicAdd(&deg[d], 1);
}

__global__ void k_dis(const int* __restrict__ deg, float* __restrict__ dis, int N) {
    int n = blockIdx.x * blockDim.x + threadIdx.x;
    if (n >= N) return;
    dis[n] = 1.0f / sqrtf((float)(deg[n] + 1));
}

__global__ void k_scan_block(const int* __restrict__ deg, int* __restrict__ rowptr,
                             int* __restrict__ partial, int N) {
    __shared__ int s[256];
    int gid = blockIdx.x * 256 + threadIdx.x;
    int v = (gid < N) ? deg[gid] : 0;
    s[threadIdx.x] = v;
    __syncthreads();
    for (int off = 1; off < 256; off <<= 1) {
        int t = (threadIdx.x >= off) ? s[threadIdx.x - off] : 0;
        __syncthreads();
        s[threadIdx.x] += t;
        __syncthreads();
    }
    if (gid < N) rowptr[gid] = s[threadIdx.x] - v;
    if (threadIdx.x == 255) partial[blockIdx.x] = s[255];
}

__global__ void k_scan_partial(int* __restrict__ partial, int nb) {
    __shared__ int s[256];
    int i = threadIdx.x;
    int v = (i < nb) ? partial[i] : 0;
    s[i] = v;
    __syncthreads();
    for (int off = 1; off < 256; off <<= 1) {
        int t = (i >= off) ? s[i - off] : 0;
        __syncthreads();
        s[i] += t;
        __syncthreads();
    }
    if (i < nb) partial[i] = s[i] - v;
}

__global__ void k_add_off(int* __restrict__ rowptr, const int* __restrict__ partial,
                          int N, int E) {
    int gid = blockIdx.x * 256 + threadIdx.x;
    if (gid < N) rowptr[gid] += partial[blockIdx.x];
    if (gid == 0) rowptr[N] = E;
}

__global__ void k_scatter(const void* __restrict__ ei, const int* __restrict__ flag,
                          const float* __restrict__ dis, const int* __restrict__ rowptr,
                          int* __restrict__ cnt, int2* __restrict__ epack, int E) {
    int e = blockIdx.x * blockDim.x + threadIdx.x;
    if (e >= E) return;
    int w64 = *flag;
    int s = ld_idx(ei, e, w64);
    int d = ld_idx(ei, (long long)E + e, w64);
    int pos = rowptr[d] + atomicAdd(&cnt[d], 1);
    epack[pos] = make_int2(s, __float_as_int(dis[s] * dis[d]));
}

// ---------------- weight: W[k][c] fp32 -> Wh fp16 [c][k] (transposed) ----------------

__global__ void k_split_w(const float* __restrict__ W, _Float16* __restrict__ Wh) {
    int k = threadIdx.x;   // 0..255
    int c = blockIdx.x;    // 0..255
    Wh[c * CH + k] = (_Float16)W[k * CH + c];
}

// ---------------- input quantize: fp32 x -> int16 rows + per-node scale ----------------

__global__ __launch_bounds__(256) void k_quant_x(const float* __restrict__ x,
                                                 uint8_t* __restrict__ Xout,
                                                 float* __restrict__ sout, int N) {
    int node = blockIdx.x * 4 + threadIdx.y;
    if (node >= N) return;
    int lane = threadIdx.x;
    float4 v = ((const float4*)(x + (size_t)node * CH))[lane];
    float mx = fmaxf(fmaxf(fabsf(v.x), fabsf(v.y)), fmaxf(fabsf(v.z), fabsf(v.w)));
    #pragma unroll
    for (int off = 32; off > 0; off >>= 1)
        mx = fmaxf(mx, __shfl_xor(mx, off));
    float inv = (mx > 0.f) ? (32767.0f / mx) : 0.f;
    short4 q;
    q.x = (short)__float2int_rn(v.x * inv);
    q.y = (short)__float2int_rn(v.y * inv);
    q.z = (short)__float2int_rn(v.z * inv);
    q.w = (short)__float2int_rn(v.w * inv);
    *(short4*)(Xout + (size_t)node * 512 + (size_t)lane * 8) = q;
    if (lane == 0) sout[node] = mx * (1.0f / 32767.0f);
}

// ---------------- GEMM (int16 A as fp16, fp16 B, late scale fold) ----------------
// H16[M][512B] = quant16(s_row * (Aq @ Wh)); Wh fp16 transposed [c][k].
// A staged int16 to LDS; fragments cvt i16->f16 (scale folded post-loop).
// Block: 128x128 output, 4 waves of 64x64, MFMA 16x16x32_f16, K-step 32.
// Per-(tile,half) scale in scales[node*2+half].

#define GM 128
#define GN 128
#define GK 32

__global__ __launch_bounds__(256, 2)
void k_gemm16(const uint8_t* __restrict__ X16, const float* __restrict__ sx,
              const _Float16* __restrict__ Bh,
              uint8_t* __restrict__ H16, float* __restrict__ scales, int M) {
    __shared__ __align__(16) char smem[65536];
    short*    lA16 = (short*)smem;              // [2][128*32] int16 = 16 KB
    _Float16* lB   = (_Float16*)(smem + 16384); // [2][128*32] f16 = 16 KB (epilogue reuses all)

    const int tid  = threadIdx.x;
    const int lane = tid & 63;
    const int wid  = tid >> 6;
    const int m0   = blockIdx.x * GM;
    const int n0   = blockIdx.y * GN;
    const int wm   = wid >> 1, wn = wid & 1;
    const int r15  = lane & 15, kg = lane >> 4;

    // stage one K-step tile: A = 512 chunks(16B), Bh = 512 -> 16 calls, 4/wave
    auto stage = [&](int buf, int k0) {
        #pragma unroll
        for (int c = 0; c < 4; c++) {
            int call = wid * 4 + c;                 // wave-uniform 0..15
            int cc = call & 7;
            int L = cc * 64 + lane;                 // 0..511
            int row = L >> 2, ch = L & 3;
            int sch = ch ^ ((row >> 1) & 3);        // both-sides chunk swizzle
            if (call < 8) {                         // A int16: 128 rows x 4 chunks
                int gr = m0 + row; gr = (gr < M) ? gr : (M - 1);
                const uint8_t* g = X16 + (size_t)gr * 512 + (size_t)k0 * 2 + (sch << 4);
                __builtin_amdgcn_global_load_lds(GLOB(g), LDSP(&lA16[buf * 4096 + L * 8]), 16, 0, 0);
            } else {                                // B fp16: 128 rows x 4 chunks
                const _Float16* g = Bh + (size_t)(n0 + row) * CH + k0 + (sch << 3);
                __builtin_amdgcn_global_load_lds(GLOB(g), LDSP(&lB[buf * 4096 + L * 8]), 16, 0, 0);
            }
        }
    };

    f32x4 acc[4][4];
    #pragma unroll
    for (int i = 0; i < 4; i++)
        #pragma unroll
        for (int n = 0; n < 4; n++)
            acc[i][n] = (f32x4){0.f, 0.f, 0.f, 0.f};

    stage(0, 0);
    __syncthreads();

    for (int ks = 0; ks < 8; ks++) {
        int cur = ks & 1;
        if (ks < 7) stage(cur ^ 1, (ks + 1) * GK);

        f16x8 aq[4], bh[4];
        #pragma unroll
        for (int i = 0; i < 4; i++) {
            int R = wm * 64 + i * 16 + r15;
            int p = kg ^ ((R >> 1) & 3);
            short8 q = *(const short8*)&lA16[cur * 4096 + R * 32 + p * 8];
            #pragma unroll
            for (int j = 0; j < 8; j++)
                aq[i][j] = (_Float16)q[j];          // v_cvt_f16_i16; scale folded later
        }
        #pragma unroll
        for (int n = 0; n < 4; n++) {
            int C = wn * 64 + n * 16 + r15;
            int p = kg ^ ((C >> 1) & 3);
            bh[n] = *(const f16x8*)&lB[cur * 4096 + C * GK + p * 8];
        }
        #pragma unroll
        for (int i = 0; i < 4; i++)
            #pragma unroll
            for (int n = 0; n < 4; n++)
                acc[i][n] = __builtin_amdgcn_mfma_f32_16x16x32_f16(aq[i], bh[n], acc[i][n], 0, 0, 0);
        __syncthreads();
    }

    // ---- fold row-uniform input scale into the accumulator ----
    float sC[4][4];
    #pragma unroll
    for (int i = 0; i < 4; i++)
        #pragma unroll
        for (int r = 0; r < 4; r++) {
            int gr = m0 + wm * 64 + i * 16 + kg * 4 + r;
            sC[i][r] = sx[(gr < M) ? gr : (M - 1)];
        }
    #pragma unroll
    for (int i = 0; i < 4; i++)
        #pragma unroll
        for (int n = 0; n < 4; n++)
            #pragma unroll
            for (int r = 0; r < 4; r++)
                acc[i][n][r] *= sC[i][r];

    // ---- epilogue: tile absmax -> scale, transpose via LDS, int16 store ----
    float mx = 0.f;
    #pragma unroll
    for (int i = 0; i < 4; i++)
        #pragma unroll
        for (int n = 0; n < 4; n++)
            #pragma unroll
            for (int r = 0; r < 4; r++)
                mx = fmaxf(mx, fabsf(acc[i][n][r]));
    #pragma unroll
    for (int off = 32; off > 0; off >>= 1)
        mx = fmaxf(mx, __shfl_xor(mx, off));
    if (lane == 0) ((float*)smem)[wid] = mx;
    __syncthreads();
    float tmax = fmaxf(fmaxf(((float*)smem)[0], ((float*)smem)[1]),
                       fmaxf(((float*)smem)[2], ((float*)smem)[3]));
    float scl = tmax * (1.0f / 32767.0f);
    float inv = (tmax > 0.f) ? (32767.0f / tmax) : 0.f;
    __syncthreads();

    float* ep = (float*)smem + wid * 4096;   // 64x64 fp32 tile per wave (16 KB)
    #pragma unroll
    for (int i = 0; i < 4; i++)
        #pragma unroll
        for (int n = 0; n < 4; n++)
            #pragma unroll
            for (int r = 0; r < 4; r++)
                ep[(i * 16 + kg * 4 + r) * 64 + n * 16 + r15] = acc[i][n][r];
    __syncthreads();

    int q = lane & 15;            // channel quad within tile
    int rsub = lane >> 4;         // row sub-index
    #pragma unroll
    for (int p = 0; p < 16; p++) {
        int lrow = p * 4 + rsub;                    // 0..63
        int grow = m0 + wm * 64 + lrow;
        if (grow < M) {
            int q0 = __float2int_rn(ep[lrow * 64 + q * 4 + 0] * inv);
            int q1 = __float2int_rn(ep[lrow * 64 + q * 4 + 1] * inv);
            int q2 = __float2int_rn(ep[lrow * 64 + q * 4 + 2] * inv);
            int q3 = __float2int_rn(ep[lrow * 64 + q * 4 + 3] * inv);
            uint2 d;
            d.x = (q0 & 0xFFFF) | (q1 << 16);
            d.y = (q2 & 0xFFFF) | (q3 << 16);
            int col = n0 + wn * 64 + q * 4;
            *(uint2*)(H16 + (size_t)grow * 512 + (size_t)col * 2) = d;
        }
    }

    if (tid < GM && m0 + tid < M) scales[(size_t)(m0 + tid) * 2 + (n0 >> 7)] = scl;
}

// ---------------- sparse aggregation (gather-CSR over int16 H) ----------------
// out[n] = dis[n]^2*h[n] + sum_e norm_e * h[src_e] (+bias)
// MODE 0: gelu -> per-node absmax -> int16 quantize to Xout + sxout (layers 1,2)
// MODE 1: fp32 store to out (layer 3, no gelu)

template <int MODE>
__global__ __launch_bounds__(256) void k_agg(const uint8_t* __restrict__ H16,
                                             const float* __restrict__ scales,
                                             const float* __restrict__ dis,
                                             const int* __restrict__ rowptr,
                                             const int2* __restrict__ epack,
                                             const float* __restrict__ bias,
                                             float* __restrict__ out,
                                             uint8_t* __restrict__ Xout,
                                             float* __restrict__ sxout, int N) {
    int node = blockIdx.x * 4 + threadIdx.y;
    if (node >= N) return;
    int lane = threadIdx.x;  // 0..63
    int half = lane >> 5;    // which 128-ch half this lane's 4 channels live in
    float d = dis[node];
    short4 hv = *(const short4*)(H16 + (size_t)node * 512 + (size_t)lane * 8);
    float wself = d * d * scales[(size_t)node * 2 + half];
    float ax = wself * (float)hv.x, ay = wself * (float)hv.y;
    float az = wself * (float)hv.z, aw = wself * (float)hv.w;
    int s = rowptr[node], e = rowptr[node + 1];
    int j = s;
    for (; j + 8 <= e; j += 8) {
        int2 p[8];
        #pragma unroll
        for (int t = 0; t < 8; t++) p[t] = epack[j + t];
        short4 v[8];
        float sc[8];
        #pragma unroll
        for (int t = 0; t < 8; t++) {
            v[t] = *(const short4*)(H16 + (size_t)p[t].x * 512 + (size_t)lane * 8);
            sc[t] = scales[(size_t)p[t].x * 2 + half];
        }
        #pragma unroll
        for (int t = 0; t < 8; t++) {
            float wn = __int_as_float(p[t].y) * sc[t];
            ax += wn * (float)v[t].x; ay += wn * (float)v[t].y;
            az += wn * (float)v[t].z; aw += wn * (float)v[t].w;
        }
    }
    for (; j < e; j++) {
        int2 p = epack[j];
        float wn = __int_as_float(p.y) * scales[(size_t)p.x * 2 + half];
        short4 v = *(const short4*)(H16 + (size_t)p.x * 512 + (size_t)lane * 8);
        ax += wn * (float)v.x; ay += wn * (float)v.y;
        az += wn * (float)v.z; aw += wn * (float)v.w;
    }
    float4 b = ((const float4*)bias)[lane];
    ax += b.x; ay += b.y; az += b.z; aw += b.w;
    if (MODE == 0) {
        ax = gelu_f(ax); ay = gelu_f(ay); az = gelu_f(az); aw = gelu_f(aw);
        float mx = fmaxf(fmaxf(fabsf(ax), fabsf(ay)), fmaxf(fabsf(az), fabsf(aw)));
        #pragma unroll
        for (int off = 32; off > 0; off >>= 1)
            mx = fmaxf(mx, __shfl_xor(mx, off));
        float inv = (mx > 0.f) ? (32767.0f / mx) : 0.f;
        short4 q;
        q.x = (short)__float2int_rn(ax * inv);
        q.y = (short)__float2int_rn(ay * inv);
        q.z = (short)__float2int_rn(az * inv);
        q.w = (short)__float2int_rn(aw * inv);
        *(short4*)(Xout + (size_t)node * 512 + (size_t)lane * 8) = q;
        if (lane == 0) sxout[node] = mx * (1.0f / 32767.0f);
    } else {
        ((float4*)(out + (size_t)node * CH))[lane] = make_float4(ax, ay, az, aw);
    }
}

// ---------------- launcher ----------------

extern "C" void kernel_launch(void* const* d_in, const int* in_sizes, int n_in,
                              void* d_out, int out_size, void* d_ws, size_t ws_size,
                              hipStream_t stream) {
    const float* x  = (const float*)d_in[0];
    const void*  ei = d_in[1];
    const float* W1 = (const float*)d_in[3]; const float* b1 = (const float*)d_in[4];
    const float* W2 = (const float*)d_in[5]; const float* b2 = (const float*)d_in[6];
    const float* W3 = (const float*)d_in[7]; const float* b3 = (const float*)d_in[8];

    int N = in_sizes[0] / CH;
    int E = in_sizes[1] / 2;
    float* out = (float*)d_out;

    char* ws = (char*)d_ws;
    auto take = [&](size_t bytes) {
        char* p = ws;
        ws += (bytes + 15) & ~(size_t)15;
        return p;
    };
    uint8_t*  H16    = (uint8_t*) take((size_t)N * 512);
    uint8_t*  Xa     = (uint8_t*) take((size_t)N * 512);
    uint8_t*  Xb     = (uint8_t*) take((size_t)N * 512);
    float*    hscl   = (float*)   take((size_t)N * 2 * sizeof(float));
    float*    sxa    = (float*)   take((size_t)N * sizeof(float));
    float*    sxb    = (float*)   take((size_t)N * sizeof(float));
    int*      deg    = (int*)     take((size_t)N * sizeof(int));
    float*    dis    = (float*)   take((size_t)N * sizeof(float));
    int*      rowptr = (int*)     take((size_t)(N + 1) * sizeof(int));
    int*      cnt    = (int*)     take((size_t)N * sizeof(int));
    int*      part   = (int*)     take(4096);
    int*      flag   = (int*)     take(16);
    int2*     epack  = (int2*)    take((size_t)E * sizeof(int2));
    _Float16* Wh1    = (_Float16*)take((size_t)CH * CH * 2);
    _Float16* Wh2    = (_Float16*)take((size_t)CH * CH * 2);
    _Float16* Wh3    = (_Float16*)take((size_t)CH * CH * 2);

    hipMemsetAsync(deg, 0, (size_t)N * sizeof(int), stream);
    hipMemsetAsync(cnt, 0, (size_t)N * sizeof(int), stream);

    int eb = (E + 255) / 256;
    int nb = (N + 255) / 256;

    k_detect<<<1, 64, 0, stream>>>(ei, flag, E);
    k_deg<<<eb, 256, 0, stream>>>(ei, flag, deg, E);
    k_dis<<<nb, 256, 0, stream>>>(deg, dis, N);
    k_scan_block<<<nb, 256, 0, stream>>>(deg, rowptr, part, N);
    k_scan_partial<<<1, 256, 0, stream>>>(part, nb);
    k_add_off<<<nb, 256, 0, stream>>>(rowptr, part, N, E);
    k_scatter<<<eb, 256, 0, stream>>>(ei, flag, dis, rowptr, cnt, epack, E);

    k_split_w<<<CH, CH, 0, stream>>>(W1, Wh1);
    k_split_w<<<CH, CH, 0, stream>>>(W2, Wh2);
    k_split_w<<<CH, CH, 0, stream>>>(W3, Wh3);

    dim3 qgrid((N + 3) / 4);
    dim3 qblock(64, 4);
    k_quant_x<<<qgrid, qblock, 0, stream>>>(x, Xa, sxa, N);

    dim3 ggrid((N + GM - 1) / GM, CH / GN);
    dim3 agrid((N + 3) / 4);
    dim3 ablock(64, 4);

    // layer 1: Xa -> H16 -> Xb
    k_gemm16<<<ggrid, 256, 0, stream>>>(Xa, sxa, Wh1, H16, hscl, N);
    k_agg<0><<<agrid, ablock, 0, stream>>>(H16, hscl, dis, rowptr, epack, b1, out, Xb, sxb, N);
    // layer 2: Xb -> H16 -> Xa
    k_gemm16<<<ggrid, 256, 0, stream>>>(Xb, sxb, Wh2, H16, hscl, N);
    k_agg<0><<<agrid, ablock, 0, stream>>>(H16, hscl, dis, rowptr, epack, b2, out, Xa, sxa, N);
    // layer 3: Xa -> H16 -> out (fp32, no gelu)
    k_gemm16<<<ggrid, 256, 0, stream>>>(Xa, sxa, Wh3, H16, hscl, N);
    k_agg<1><<<agrid, ablock, 0, stream>>>(H16, hscl, dis, rowptr, epack, b3, out, Xb, sxb, N);
}

// Round 16
// 385.599 us; speedup vs baseline: 1.7750x; 1.0112x over previous
//
#include <hip/hip_runtime.h>
#include <cstdint>
#include <cstddef>

#define CH 256      // all layers are 256-channel

typedef _Float16 f16x8 __attribute__((ext_vector_type(8)));
typedef _Float16 f16x4 __attribute__((ext_vector_type(4)));
typedef float f32x4 __attribute__((ext_vector_type(4)));
typedef short short8 __attribute__((ext_vector_type(8)));

#define GLOB(x) ((const __attribute__((address_space(1))) void*)(x))
#define LDSP(x) ((__attribute__((address_space(3))) void*)(x))

// ---------------- helpers ----------------

__device__ __forceinline__ int ld_idx(const void* p, long long i, int w64) {
    if (w64) return (int)((const long long*)p)[i];
    return ((const int*)p)[i];
}

__device__ __forceinline__ float gelu_f(float x) {
    float x3 = x * x * x;
    float t = tanhf(0.7978845608028654f * (x + 0.044715f * x3));
    return 0.5f * x * (1.0f + t);
}

// ---------------- preprocessing ----------------

__global__ void k_detect(const void* __restrict__ ei, int* __restrict__ flag, int E) {
    int l = threadIdx.x;  // 0..63
    long long k = ((long long)l * (long long)(E - 1)) / 63;
    int w = ((const int*)ei)[2 * k + 1];
    unsigned long long vote = __ballot(w == 0);
    if (l == 0) *flag = (vote == ~0ULL) ? 1 : 0;
}

__global__ void k_deg(const void* __restrict__ ei, const int* __restrict__ flag,
                      int* __restrict__ deg, int E) {
    int e = blockIdx.x * blockDim.x + threadIdx.x;
    if (e >= E) return;
    int w64 = *flag;
    int d = ld_idx(ei, (long long)E + e, w64);
    atomicAdd(&deg[d], 1);
}

__global__ void k_scan_block(const int* __restrict__ deg, int* __restrict__ rowptr,
                             int* __restrict__ partial, int N) {
    __shared__ int s[256];
    int gid = blockIdx.x * 256 + threadIdx.x;
    int v = (gid < N) ? deg[gid] : 0;
    s[threadIdx.x] = v;
    __syncthreads();
    for (int off = 1; off < 256; off <<= 1) {
        int t = (threadIdx.x >= off) ? s[threadIdx.x - off] : 0;
        __syncthreads();
        s[threadIdx.x] += t;
        __syncthreads();
    }
    if (gid < N) rowptr[gid] = s[threadIdx.x] - v;
    if (threadIdx.x == 255) partial[blockIdx.x] = s[255];
}

__global__ void k_scan_partial(int* __restrict__ partial, int nb) {
    __shared__ int s[256];
    int i = threadIdx.x;
    int v = (i < nb) ? partial[i] : 0;
    s[i] = v;
    __syncthreads();
    for (int off = 1; off < 256; off <<= 1) {
        int t = (i >= off) ? s[i - off] : 0;
        __syncthreads();
        s[i] += t;
        __syncthreads();
    }
    if (i < nb) partial[i] = s[i] - v;
}

// fused: rowptr offset add + dis computation
__global__ void k_add_off(int* __restrict__ rowptr, const int* __restrict__ partial,
                          const int* __restrict__ deg, float* __restrict__ dis,
                          int N, int E) {
    int gid = blockIdx.x * 256 + threadIdx.x;
    if (gid < N) {
        rowptr[gid] += partial[blockIdx.x];
        dis[gid] = 1.0f / sqrtf((float)(deg[gid] + 1));
    }
    if (gid == 0) rowptr[N] = E;
}

// src-only scatter (norm folded into per-node comb scales; no dis needed here)
__global__ void k_scatter(const void* __restrict__ ei, const int* __restrict__ flag,
                          const int* __restrict__ rowptr, int* __restrict__ cnt,
                          int* __restrict__ ssrc, int E) {
    int e = blockIdx.x * blockDim.x + threadIdx.x;
    if (e >= E) return;
    int w64 = *flag;
    int s = ld_idx(ei, e, w64);
    int d = ld_idx(ei, (long long)E + e, w64);
    int pos = rowptr[d] + atomicAdd(&cnt[d], 1);
    ssrc[pos] = s;
}

// ---------------- weights: 3x W[k][c] fp32 -> Wh fp16 [c][k] (one launch) ----------------

__global__ void k_split_w3(const float* __restrict__ W1, const float* __restrict__ W2,
                           const float* __restrict__ W3, _Float16* __restrict__ Wh1,
                           _Float16* __restrict__ Wh2, _Float16* __restrict__ Wh3) {
    const float* W = (blockIdx.y == 0) ? W1 : (blockIdx.y == 1) ? W2 : W3;
    _Float16*   Wh = (blockIdx.y == 0) ? Wh1 : (blockIdx.y == 1) ? Wh2 : Wh3;
    int k = threadIdx.x;   // 0..255
    int c = blockIdx.x;    // 0..255
    Wh[c * CH + k] = (_Float16)W[k * CH + c];
}

// ---------------- input quantize: fp32 x -> int16 rows + per-node scale ----------------

__global__ __launch_bounds__(256) void k_quant_x(const float* __restrict__ x,
                                                 uint8_t* __restrict__ Xout,
                                                 float* __restrict__ sout, int N) {
    int node = blockIdx.x * 4 + threadIdx.y;
    if (node >= N) return;
    int lane = threadIdx.x;
    float4 v = ((const float4*)(x + (size_t)node * CH))[lane];
    float mx = fmaxf(fmaxf(fabsf(v.x), fabsf(v.y)), fmaxf(fabsf(v.z), fabsf(v.w)));
    #pragma unroll
    for (int off = 32; off > 0; off >>= 1)
        mx = fmaxf(mx, __shfl_xor(mx, off));
    float inv = (mx > 0.f) ? (32767.0f / mx) : 0.f;
    short4 q;
    q.x = (short)__float2int_rn(v.x * inv);
    q.y = (short)__float2int_rn(v.y * inv);
    q.z = (short)__float2int_rn(v.z * inv);
    q.w = (short)__float2int_rn(v.w * inv);
    *(short4*)(Xout + (size_t)node * 512 + (size_t)lane * 8) = q;
    if (lane == 0) sout[node] = mx * (1.0f / 32767.0f);
}

// ---------------- GEMM (int16 A as fp16, fp16 B, late scale fold) ----------------
// H16[M][512B] = quant16(s_row * (Aq @ Wh)); Wh fp16 transposed [c][k].
// comb-scale output: hcomb[node*2+half] = hscale * dis[node]  (folds the src-side
// of the symmetric norm so agg needs only src indices).
// Block: 128x128 output, 4 waves of 64x64, MFMA 16x16x32_f16, K-step 32.

#define GM 128
#define GN 128
#define GK 32

__global__ __launch_bounds__(256, 2)
void k_gemm16(const uint8_t* __restrict__ X16, const float* __restrict__ sx,
              const _Float16* __restrict__ Bh, const float* __restrict__ dis,
              uint8_t* __restrict__ H16, float* __restrict__ hcomb, int M) {
    __shared__ __align__(16) char smem[65536];
    short*    lA16 = (short*)smem;              // [2][128*32] int16 = 16 KB
    _Float16* lB   = (_Float16*)(smem + 16384); // [2][128*32] f16 = 16 KB (epilogue reuses all)

    const int tid  = threadIdx.x;
    const int lane = tid & 63;
    const int wid  = tid >> 6;
    const int m0   = blockIdx.x * GM;
    const int n0   = blockIdx.y * GN;
    const int wm   = wid >> 1, wn = wid & 1;
    const int r15  = lane & 15, kg = lane >> 4;

    // stage one K-step tile: A = 512 chunks(16B), Bh = 512 -> 16 calls, 4/wave
    auto stage = [&](int buf, int k0) {
        #pragma unroll
        for (int c = 0; c < 4; c++) {
            int call = wid * 4 + c;                 // wave-uniform 0..15
            int cc = call & 7;
            int L = cc * 64 + lane;                 // 0..511
            int row = L >> 2, ch = L & 3;
            int sch = ch ^ ((row >> 1) & 3);        // both-sides chunk swizzle
            if (call < 8) {                         // A int16: 128 rows x 4 chunks
                int gr = m0 + row; gr = (gr < M) ? gr : (M - 1);
                const uint8_t* g = X16 + (size_t)gr * 512 + (size_t)k0 * 2 + (sch << 4);
                __builtin_amdgcn_global_load_lds(GLOB(g), LDSP(&lA16[buf * 4096 + L * 8]), 16, 0, 0);
            } else {                                // B fp16: 128 rows x 4 chunks
                const _Float16* g = Bh + (size_t)(n0 + row) * CH + k0 + (sch << 3);
                __builtin_amdgcn_global_load_lds(GLOB(g), LDSP(&lB[buf * 4096 + L * 8]), 16, 0, 0);
            }
        }
    };

    f32x4 acc[4][4];
    #pragma unroll
    for (int i = 0; i < 4; i++)
        #pragma unroll
        for (int n = 0; n < 4; n++)
            acc[i][n] = (f32x4){0.f, 0.f, 0.f, 0.f};

    stage(0, 0);
    __syncthreads();

    for (int ks = 0; ks < 8; ks++) {
        int cur = ks & 1;
        if (ks < 7) stage(cur ^ 1, (ks + 1) * GK);

        f16x8 aq[4], bh[4];
        #pragma unroll
        for (int i = 0; i < 4; i++) {
            int R = wm * 64 + i * 16 + r15;
            int p = kg ^ ((R >> 1) & 3);
            short8 q = *(const short8*)&lA16[cur * 4096 + R * 32 + p * 8];
            #pragma unroll
            for (int j = 0; j < 8; j++)
                aq[i][j] = (_Float16)q[j];          // v_cvt_f16_i16; scale folded later
        }
        #pragma unroll
        for (int n = 0; n < 4; n++) {
            int C = wn * 64 + n * 16 + r15;
            int p = kg ^ ((C >> 1) & 3);
            bh[n] = *(const f16x8*)&lB[cur * 4096 + C * GK + p * 8];
        }
        #pragma unroll
        for (int i = 0; i < 4; i++)
            #pragma unroll
            for (int n = 0; n < 4; n++)
                acc[i][n] = __builtin_amdgcn_mfma_f32_16x16x32_f16(aq[i], bh[n], acc[i][n], 0, 0, 0);
        __syncthreads();
    }

    // ---- fold row-uniform input scale into the accumulator ----
    float sC[4][4];
    #pragma unroll
    for (int i = 0; i < 4; i++)
        #pragma unroll
        for (int r = 0; r < 4; r++) {
            int gr = m0 + wm * 64 + i * 16 + kg * 4 + r;
            sC[i][r] = sx[(gr < M) ? gr : (M - 1)];
        }
    #pragma unroll
    for (int i = 0; i < 4; i++)
        #pragma unroll
        for (int n = 0; n < 4; n++)
            #pragma unroll
            for (int r = 0; r < 4; r++)
                acc[i][n][r] *= sC[i][r];

    // ---- epilogue: tile absmax -> scale, transpose via LDS, int16 store ----
    float mx = 0.f;
    #pragma unroll
    for (int i = 0; i < 4; i++)
        #pragma unroll
        for (int n = 0; n < 4; n++)
            #pragma unroll
            for (int r = 0; r < 4; r++)
                mx = fmaxf(mx, fabsf(acc[i][n][r]));
    #pragma unroll
    for (int off = 32; off > 0; off >>= 1)
        mx = fmaxf(mx, __shfl_xor(mx, off));
    if (lane == 0) ((float*)smem)[wid] = mx;
    __syncthreads();
    float tmax = fmaxf(fmaxf(((float*)smem)[0], ((float*)smem)[1]),
                       fmaxf(((float*)smem)[2], ((float*)smem)[3]));
    float scl = tmax * (1.0f / 32767.0f);
    float inv = (tmax > 0.f) ? (32767.0f / tmax) : 0.f;
    __syncthreads();

    float* ep = (float*)smem + wid * 4096;   // 64x64 fp32 tile per wave (16 KB)
    #pragma unroll
    for (int i = 0; i < 4; i++)
        #pragma unroll
        for (int n = 0; n < 4; n++)
            #pragma unroll
            for (int r = 0; r < 4; r++)
                ep[(i * 16 + kg * 4 + r) * 64 + n * 16 + r15] = acc[i][n][r];
    __syncthreads();

    int q = lane & 15;            // channel quad within tile
    int rsub = lane >> 4;         // row sub-index
    #pragma unroll
    for (int p = 0; p < 16; p++) {
        int lrow = p * 4 + rsub;                    // 0..63
        int grow = m0 + wm * 64 + lrow;
        if (grow < M) {
            int q0 = __float2int_rn(ep[lrow * 64 + q * 4 + 0] * inv);
            int q1 = __float2int_rn(ep[lrow * 64 + q * 4 + 1] * inv);
            int q2 = __float2int_rn(ep[lrow * 64 + q * 4 + 2] * inv);
            int q3 = __float2int_rn(ep[lrow * 64 + q * 4 + 3] * inv);
            uint2 d;
            d.x = (q0 & 0xFFFF) | (q1 << 16);
            d.y = (q2 & 0xFFFF) | (q3 << 16);
            int col = n0 + wn * 64 + q * 4;
            *(uint2*)(H16 + (size_t)grow * 512 + (size_t)col * 2) = d;
        }
    }

    // comb scale: fold dis[node] so agg's edge weight = dis[dst] * hcomb[src]
    if (tid < GM && m0 + tid < M)
        hcomb[(size_t)(m0 + tid) * 2 + (n0 >> 7)] = scl * dis[m0 + tid];
}

// ---------------- sparse aggregation (gather-CSR over int16 H, src-only edges) --------
// out[n] = d * ( hcomb[n]*h[n] + sum_e hcomb[src_e]*h[src_e] ) + bias, d = dis[n]
// (hcomb already contains one dis factor; self term = d * hcomb[n] = dis^2 * hscale.)
// MODE 0: gelu -> per-node absmax -> int16 quantize to Xout + sxout (layers 1,2)
// MODE 1: fp32 store to out (layer 3, no gelu)

template <int MODE>
__global__ __launch_bounds__(256) void k_agg(const uint8_t* __restrict__ H16,
                                             const float* __restrict__ hcomb,
                                             const float* __restrict__ dis,
                                             const int* __restrict__ rowptr,
                                             const int* __restrict__ ssrc,
                                             const float* __restrict__ bias,
                                             float* __restrict__ out,
                                             uint8_t* __restrict__ Xout,
                                             float* __restrict__ sxout, int N) {
    int node = blockIdx.x * 4 + threadIdx.y;
    if (node >= N) return;
    int lane = threadIdx.x;  // 0..63
    int half = lane >> 5;    // which 128-ch half this lane's 4 channels live in
    float d = dis[node];
    short4 hv = *(const short4*)(H16 + (size_t)node * 512 + (size_t)lane * 8);
    float wself = d * hcomb[(size_t)node * 2 + half];   // = dis^2 * hscale (fixed: no extra *d)
    float ax = wself * (float)hv.x, ay = wself * (float)hv.y;
    float az = wself * (float)hv.z, aw = wself * (float)hv.w;
    int s = rowptr[node], e = rowptr[node + 1];
    int j = s;
    for (; j + 8 <= e; j += 8) {
        int p[8];
        #pragma unroll
        for (int t = 0; t < 8; t++) p[t] = ssrc[j + t];
        short4 v[8];
        float sc[8];
        #pragma unroll
        for (int t = 0; t < 8; t++) {
            v[t] = *(const short4*)(H16 + (size_t)p[t] * 512 + (size_t)lane * 8);
            sc[t] = hcomb[(size_t)p[t] * 2 + half];
        }
        #pragma unroll
        for (int t = 0; t < 8; t++) {
            float wn = d * sc[t];
            ax += wn * (float)v[t].x; ay += wn * (float)v[t].y;
            az += wn * (float)v[t].z; aw += wn * (float)v[t].w;
        }
    }
    for (; j < e; j++) {
        int p = ssrc[j];
        float wn = d * hcomb[(size_t)p * 2 + half];
        short4 v = *(const short4*)(H16 + (size_t)p * 512 + (size_t)lane * 8);
        ax += wn * (float)v.x; ay += wn * (float)v.y;
        az += wn * (float)v.z; aw += wn * (float)v.w;
    }
    float4 b = ((const float4*)bias)[lane];
    ax += b.x; ay += b.y; az += b.z; aw += b.w;
    if (MODE == 0) {
        ax = gelu_f(ax); ay = gelu_f(ay); az = gelu_f(az); aw = gelu_f(aw);
        float mx = fmaxf(fmaxf(fabsf(ax), fabsf(ay)), fmaxf(fabsf(az), fabsf(aw)));
        #pragma unroll
        for (int off = 32; off > 0; off >>= 1)
            mx = fmaxf(mx, __shfl_xor(mx, off));
        float inv = (mx > 0.f) ? (32767.0f / mx) : 0.f;
        short4 q;
        q.x = (short)__float2int_rn(ax * inv);
        q.y = (short)__float2int_rn(ay * inv);
        q.z = (short)__float2int_rn(az * inv);
        q.w = (short)__float2int_rn(aw * inv);
        *(short4*)(Xout + (size_t)node * 512 + (size_t)lane * 8) = q;
        if (lane == 0) sxout[node] = mx * (1.0f / 32767.0f);
    } else {
        ((float4*)(out + (size_t)node * CH))[lane] = make_float4(ax, ay, az, aw);
    }
}

// ---------------- launcher ----------------

extern "C" void kernel_launch(void* const* d_in, const int* in_sizes, int n_in,
                              void* d_out, int out_size, void* d_ws, size_t ws_size,
                              hipStream_t stream) {
    const float* x  = (const float*)d_in[0];
    const void*  ei = d_in[1];
    const float* W1 = (const float*)d_in[3]; const float* b1 = (const float*)d_in[4];
    const float* W2 = (const float*)d_in[5]; const float* b2 = (const float*)d_in[6];
    const float* W3 = (const float*)d_in[7]; const float* b3 = (const float*)d_in[8];

    int N = in_sizes[0] / CH;
    int E = in_sizes[1] / 2;
    float* out = (float*)d_out;

    char* ws = (char*)d_ws;
    auto take = [&](size_t bytes) {
        char* p = ws;
        ws += (bytes + 15) & ~(size_t)15;
        return p;
    };
    uint8_t*  H16    = (uint8_t*) take((size_t)N * 512);
    uint8_t*  Xa     = (uint8_t*) take((size_t)N * 512);
    uint8_t*  Xb     = (uint8_t*) take((size_t)N * 512);
    float*    hcomb  = (float*)   take((size_t)N * 2 * sizeof(float));
    float*    sxa    = (float*)   take((size_t)N * sizeof(float));
    float*    sxb    = (float*)   take((size_t)N * sizeof(float));
    int*      deg    = (int*)     take((size_t)N * sizeof(int));
    float*    dis    = (float*)   take((size_t)N * sizeof(float));
    int*      rowptr = (int*)     take((size_t)(N + 1) * sizeof(int));
    int*      cnt    = (int*)     take((size_t)N * sizeof(int));
    int*      part   = (int*)     take(4096);
    int*      flag   = (int*)     take(16);
    int*      ssrc   = (int*)     take((size_t)E * sizeof(int));
    _Float16* Wh1    = (_Float16*)take((size_t)CH * CH * 2);
    _Float16* Wh2    = (_Float16*)take((size_t)CH * CH * 2);
    _Float16* Wh3    = (_Float16*)take((size_t)CH * CH * 2);

    hipMemsetAsync(deg, 0, (size_t)N * sizeof(int), stream);
    hipMemsetAsync(cnt, 0, (size_t)N * sizeof(int), stream);

    int eb = (E + 255) / 256;
    int nb = (N + 255) / 256;

    k_detect<<<1, 64, 0, stream>>>(ei, flag, E);
    k_deg<<<eb, 256, 0, stream>>>(ei, flag, deg, E);
    k_scan_block<<<nb, 256, 0, stream>>>(deg, rowptr, part, N);
    k_scan_partial<<<1, 256, 0, stream>>>(part, nb);
    k_add_off<<<nb, 256, 0, stream>>>(rowptr, part, deg, dis, N, E);
    k_scatter<<<eb, 256, 0, stream>>>(ei, flag, rowptr, cnt, ssrc, E);

    dim3 wgrid(CH, 3);
    k_split_w3<<<wgrid, CH, 0, stream>>>(W1, W2, W3, Wh1, Wh2, Wh3);

    dim3 qgrid((N + 3) / 4);
    dim3 qblock(64, 4);
    k_quant_x<<<qgrid, qblock, 0, stream>>>(x, Xa, sxa, N);

    dim3 ggrid((N + GM - 1) / GM, CH / GN);
    dim3 agrid((N + 3) / 4);
    dim3 ablock(64, 4);

    // layer 1: Xa -> H16 -> Xb
    k_gemm16<<<ggrid, 256, 0, stream>>>(Xa, sxa, Wh1, dis, H16, hcomb, N);
    k_agg<0><<<agrid, ablock, 0, stream>>>(H16, hcomb, dis, rowptr, ssrc, b1, out, Xb, sxb, N);
    // layer 2: Xb -> H16 -> Xa
    k_gemm16<<<ggrid, 256, 0, stream>>>(Xb, sxb, Wh2, dis, H16, hcomb, N);
    k_agg<0><<<agrid, ablock, 0, stream>>>(H16, hcomb, dis, rowptr, ssrc, b2, out, Xa, sxa, N);
    // layer 3: Xa -> H16 -> out (fp32, no gelu)
    k_gemm16<<<ggrid, 256, 0, stream>>>(Xa, sxa, Wh3, dis, H16, hcomb, N);
    k_agg<1><<<agrid, ablock, 0, stream>>>(H16, hcomb, dis, rowptr, ssrc, b3, out, Xb, sxb, N);
}